// Round 1
// baseline (1808.620 us; speedup 1.0000x reference)
//
#include <hip/hip_runtime.h>
#include <cstdint>
#include <cstddef>

#define BB 8
#define SS 8192
#define DD 64
#define HH 8
#define NB 128
#define NCHUNK 128   /* S / 64 */
#define CHUNKS 1024  /* H * NB */

// ---------------------------------------------------------------------------
// Kernel 1: LSH hash. For each (b,h,t): bucket = argmax over [rot, -rot],
// rot[i] = sum_f qk[b,t,f] * rotations[f,h,i], i in [0,64).
// Grid: (S/64, B), block 256. Each block: one 64-row q tile, loops h.
// ---------------------------------------------------------------------------
__global__ __launch_bounds__(256) void hash_kernel(const float* __restrict__ qk,
                                                   const float* __restrict__ rot,
                                                   unsigned char* __restrict__ bucket) {
  __shared__ float qs[64][68];
  __shared__ float rs[64][68];
  const int tid = threadIdx.x;
  const int b = blockIdx.y, tile = blockIdx.x;
  const int row = tid >> 2, part = tid & 3;

  {
    const float4* src = (const float4*)(qk + ((size_t)b * SS + (size_t)tile * 64 + row) * DD + part * 16);
    float* dst = &qs[row][part * 16];
#pragma unroll
    for (int k = 0; k < 4; ++k) {
      float4 f = src[k];
      dst[k * 4 + 0] = f.x; dst[k * 4 + 1] = f.y; dst[k * 4 + 2] = f.z; dst[k * 4 + 3] = f.w;
    }
  }

  for (int h = 0; h < HH; ++h) {
    __syncthreads();  // protect rs from previous iteration's readers
    {
      const float4* src = (const float4*)(rot + (size_t)row * (HH * 64) + h * 64 + part * 16);
      float* dst = &rs[row][part * 16];
#pragma unroll
      for (int k = 0; k < 4; ++k) {
        float4 f = src[k];
        dst[k * 4 + 0] = f.x; dst[k * 4 + 1] = f.y; dst[k * 4 + 2] = f.z; dst[k * 4 + 3] = f.w;
      }
    }
    __syncthreads();

    const int t = row;
    float bestv = -3.4e38f;
    int besti = 0;
#pragma unroll
    for (int ii = 0; ii < 16; ++ii) {
      const int i = part * 16 + ii;
      float acc = 0.f;
#pragma unroll
      for (int f = 0; f < 64; ++f) acc += qs[t][f] * rs[f][i];
      if (acc > bestv || (acc == bestv && i < besti)) { bestv = acc; besti = i; }
      const float nv = -acc;
      if (nv > bestv || (nv == bestv && (i + 64) < besti)) { bestv = nv; besti = i + 64; }
    }
    // reduce across the 4 lanes covering this t (prefer larger val, then smaller idx)
#pragma unroll
    for (int off = 1; off < 4; off <<= 1) {
      const float ov = __shfl_xor(bestv, off);
      const int oi = __shfl_xor(besti, off);
      if (ov > bestv || (ov == bestv && oi < besti)) { bestv = ov; besti = oi; }
    }
    if (part == 0)
      bucket[((size_t)(b * HH + h)) * SS + (size_t)tile * 64 + t] = (unsigned char)besti;
  }
}

// ---------------------------------------------------------------------------
// Kernel 2: stable counting sort per (b,h). One block per (b,h).
// hist[bucket][chunk] in LDS, exclusive scan, in-chunk rank for stability.
// Output: sticker[bh][p] = original t at sorted position p.
// ---------------------------------------------------------------------------
__global__ __launch_bounds__(256) void sort_kernel(const unsigned char* __restrict__ bucket,
                                                   int* __restrict__ sticker) {
  __shared__ unsigned char lb[SS];
  __shared__ unsigned int hist[NB * NCHUNK];
  __shared__ unsigned int ssum[256];
  const int tid = threadIdx.x;
  const int bh = blockIdx.x;

  {
    const uint4* src = (const uint4*)(bucket + (size_t)bh * SS);
    uint4* dst = (uint4*)lb;
#pragma unroll
    for (int k = 0; k < SS / 16 / 256; ++k)  // 2 iterations
      dst[tid + k * 256] = src[tid + k * 256];
  }
#pragma unroll
  for (int k = 0; k < (NB * NCHUNK) / 256; ++k) hist[tid + k * 256] = 0u;
  __syncthreads();

  for (int t = tid; t < SS; t += 256)
    atomicAdd(&hist[(int)lb[t] * NCHUNK + (t >> 6)], 1u);
  __syncthreads();

  // exclusive scan over the 16384-entry hist (bucket-major)
  unsigned int segsum = 0u;
  const int base = tid * 64;
  for (int e = 0; e < 64; ++e) segsum += hist[base + e];
  ssum[tid] = segsum;
  __syncthreads();
  for (int off = 1; off < 256; off <<= 1) {
    const unsigned int vv = (tid >= off) ? ssum[tid - off] : 0u;
    __syncthreads();
    ssum[tid] += vv;
    __syncthreads();
  }
  unsigned int run = ssum[tid] - segsum;  // exclusive offset of this segment
  for (int e = 0; e < 64; ++e) {
    const unsigned int tv = hist[base + e];
    hist[base + e] = run;
    run += tv;
  }
  __syncthreads();

  // stable scatter: rank within (bucket, chunk) via scan of earlier items in chunk
  for (int t = tid; t < SS; t += 256) {
    const int bk = lb[t];
    const int c = t >> 6;
    int rank = 0;
    for (int t2 = c << 6; t2 < t; ++t2) rank += (lb[t2] == bk) ? 1 : 0;
    const int pos = (int)hist[bk * NCHUNK + c] + rank;
    sticker[(size_t)bh * SS + pos] = t;
  }
}

// ---------------------------------------------------------------------------
// Kernel 3: pass A — per-row logsumexp (logits). Grid (NB, H, B), block 256.
// Keys = normalized rows; query q's raw row recovered via snorm[q].
// ---------------------------------------------------------------------------
__global__ __launch_bounds__(256) void logits_kernel(const float* __restrict__ qk,
                                                     const int* __restrict__ sticker,
                                                     float* __restrict__ logits) {
  __shared__ float ks[128][68];
  __shared__ float snorm[128];
  __shared__ int tks[128];
  const int tid = threadIdx.x;
  const int bin = blockIdx.x, h = blockIdx.y, b = blockIdx.z;
  const int c = h * NB + bin;
  const int prev = (c + CHUNKS - 1) & (CHUNKS - 1);
  const int ph = prev >> 7, pbin = prev & 127;

  if (tid < 128) {
    const int j = tid;
    const int src = (j < 64) ? ((b * HH + h) * SS + bin * 64 + j)
                             : ((b * HH + ph) * SS + pbin * 64 + (j - 64));
    tks[j] = sticker[src];
  }
  __syncthreads();

  {
    const int jrow = tid >> 1, half = tid & 1;
    const float4* src = (const float4*)(qk + ((size_t)b * SS + tks[jrow]) * DD + half * 32);
    float* dst = &ks[jrow][half * 32];
    float ssq = 0.f;
#pragma unroll
    for (int k = 0; k < 8; ++k) {
      float4 f = src[k];
      dst[k * 4 + 0] = f.x; dst[k * 4 + 1] = f.y; dst[k * 4 + 2] = f.z; dst[k * 4 + 3] = f.w;
      ssq += f.x * f.x + f.y * f.y + f.z * f.z + f.w * f.w;
    }
    ssq += __shfl_xor(ssq, 1);
    const float r = rsqrtf(ssq + 1e-6f);
    const float sn = (ssq + 1e-6f) * r;  // = sqrt(ssq + eps)
#pragma unroll
    for (int k = 0; k < 32; ++k) dst[k] *= r;
    if (half == 0) snorm[jrow] = sn;
  }
  __syncthreads();

  const int q = tid >> 2, part = tid & 3;
  const int tqq = tks[q];
  const float sq = snorm[q];
  float dv[32];
  float m = -3.4e38f;
#pragma unroll
  for (int jj = 0; jj < 32; ++jj) {
    const int j = part * 32 + jj;
    float acc = 0.f;
#pragma unroll
    for (int f = 0; f < 64; ++f) acc += ks[q][f] * ks[j][f];
    float dd = acc * sq * 0.125f;
    const int tkj = tks[j];
    if (tkj > tqq) dd = -1e38f;
    else if (tkj == tqq) dd = -50000.f;
    dv[jj] = dd;
    m = fmaxf(m, dd);
  }
  m = fmaxf(m, __shfl_xor(m, 1));
  m = fmaxf(m, __shfl_xor(m, 2));
  float sum = 0.f;
#pragma unroll
  for (int jj = 0; jj < 32; ++jj) sum += __expf(dv[jj] - m);
  sum += __shfl_xor(sum, 1);
  sum += __shfl_xor(sum, 2);
  if (part == 0) logits[((size_t)(b * HH + h)) * SS + tqq] = m + logf(sum);
}

// ---------------------------------------------------------------------------
// Kernel 4: LSE over hash rounds per (b,t).
// ---------------------------------------------------------------------------
__global__ __launch_bounds__(256) void combine_lse_kernel(const float* __restrict__ logits,
                                                          float* __restrict__ lse_tot) {
  const int idx = blockIdx.x * 256 + threadIdx.x;  // idx = b*S + t
  const int b = idx >> 13, t = idx & (SS - 1);
  float l[HH];
  float m = -3.4e38f;
#pragma unroll
  for (int h = 0; h < HH; ++h) {
    l[h] = logits[((size_t)(b * HH + h)) * SS + t];
    m = fmaxf(m, l[h]);
  }
  float sum = 0.f;
#pragma unroll
  for (int h = 0; h < HH; ++h) sum += __expf(l[h] - m);
  lse_tot[idx] = m + logf(sum);
}

// ---------------------------------------------------------------------------
// Kernel 5: pass B — attention + accumulate into out. Launched once per h
// (stream-serialized so out[b,t] += is race-free & deterministic).
// Grid (NB, B), block 256.
// ---------------------------------------------------------------------------
__global__ __launch_bounds__(256) void attn_kernel(const float* __restrict__ qk,
                                                   const float* __restrict__ v,
                                                   const int* __restrict__ sticker,
                                                   const float* __restrict__ lse_tot,
                                                   float* __restrict__ out,
                                                   const int h) {
  __shared__ float ks[128][68];
  __shared__ float vs[128][68];
  __shared__ float ps[64][130];
  __shared__ float snorm[128];
  __shared__ float lseq[64];
  __shared__ int tks[128];
  const int tid = threadIdx.x;
  const int bin = blockIdx.x, b = blockIdx.y;
  const int c = h * NB + bin;
  const int prev = (c + CHUNKS - 1) & (CHUNKS - 1);
  const int ph = prev >> 7, pbin = prev & 127;

  if (tid < 128) {
    const int j = tid;
    const int src = (j < 64) ? ((b * HH + h) * SS + bin * 64 + j)
                             : ((b * HH + ph) * SS + pbin * 64 + (j - 64));
    tks[j] = sticker[src];
  }
  __syncthreads();

  {
    const int jrow = tid >> 1, half = tid & 1;
    const int trow = tks[jrow];
    {
      const float4* src = (const float4*)(qk + ((size_t)b * SS + trow) * DD + half * 32);
      float* dst = &ks[jrow][half * 32];
      float ssq = 0.f;
#pragma unroll
      for (int k = 0; k < 8; ++k) {
        float4 f = src[k];
        dst[k * 4 + 0] = f.x; dst[k * 4 + 1] = f.y; dst[k * 4 + 2] = f.z; dst[k * 4 + 3] = f.w;
        ssq += f.x * f.x + f.y * f.y + f.z * f.z + f.w * f.w;
      }
      ssq += __shfl_xor(ssq, 1);
      const float r = rsqrtf(ssq + 1e-6f);
      const float sn = (ssq + 1e-6f) * r;
#pragma unroll
      for (int k = 0; k < 32; ++k) dst[k] *= r;
      if (half == 0) snorm[jrow] = sn;
    }
    {
      const float4* src = (const float4*)(v + ((size_t)b * SS + trow) * DD + half * 32);
      float* dst = &vs[jrow][half * 32];
#pragma unroll
      for (int k = 0; k < 8; ++k) {
        float4 f = src[k];
        dst[k * 4 + 0] = f.x; dst[k * 4 + 1] = f.y; dst[k * 4 + 2] = f.z; dst[k * 4 + 3] = f.w;
      }
    }
  }
  if (tid < 64) lseq[tid] = lse_tot[b * SS + tks[tid]];
  __syncthreads();

  const int q = tid >> 2, part = tid & 3;
  const int tqq = tks[q];
  const float sq = snorm[q];
  const float lse = lseq[q];
#pragma unroll
  for (int jj = 0; jj < 32; ++jj) {
    const int j = part * 32 + jj;
    float acc = 0.f;
#pragma unroll
    for (int f = 0; f < 64; ++f) acc += ks[q][f] * ks[j][f];
    float dd = acc * sq * 0.125f;
    const int tkj = tks[j];
    float p;
    if (tkj > tqq) {
      p = 0.f;
    } else {
      if (tkj == tqq) dd = -50000.f;
      p = __expf(dd - lse);
    }
    ps[q][j] = p;
  }
  __syncthreads();

  float acc[16];
#pragma unroll
  for (int d = 0; d < 16; ++d) acc[d] = 0.f;
  const int d0 = part * 16;
  for (int j = 0; j < 128; ++j) {
    const float p = ps[q][j];
#pragma unroll
    for (int d = 0; d < 16; ++d) acc[d] += p * vs[j][d0 + d];
  }
  float4* op = (float4*)(out + ((size_t)b * SS + tqq) * DD + d0);
#pragma unroll
  for (int w = 0; w < 4; ++w) {
    float4 o = op[w];
    o.x += acc[w * 4 + 0];
    o.y += acc[w * 4 + 1];
    o.z += acc[w * 4 + 2];
    o.w += acc[w * 4 + 3];
    op[w] = o;
  }
}

// ---------------------------------------------------------------------------
extern "C" void kernel_launch(void* const* d_in, const int* in_sizes, int n_in,
                              void* d_out, int out_size, void* d_ws, size_t ws_size,
                              hipStream_t stream) {
  const float* qk = (const float*)d_in[0];
  const float* v = (const float*)d_in[1];
  const float* rot = (const float*)d_in[2];
  float* out = (float*)d_out;

  char* ws = (char*)d_ws;
  int* sticker = (int*)ws;                                            // 2 MB
  float* logits = (float*)(ws + ((size_t)2 << 20));                   // 2 MB
  float* lse_tot = (float*)(ws + ((size_t)4 << 20));                  // 256 KB
  unsigned char* bucket = (unsigned char*)(ws + ((size_t)4 << 20) + ((size_t)256 << 10));  // 512 KB

  hipMemsetAsync(d_out, 0, (size_t)BB * SS * DD * sizeof(float), stream);

  hash_kernel<<<dim3(NCHUNK, BB), 256, 0, stream>>>(qk, rot, bucket);
  sort_kernel<<<BB * HH, 256, 0, stream>>>(bucket, sticker);
  logits_kernel<<<dim3(NB, HH, BB), 256, 0, stream>>>(qk, sticker, logits);
  combine_lse_kernel<<<(BB * SS) / 256, 256, 0, stream>>>(logits, lse_tot);
  for (int h = 0; h < HH; ++h)
    attn_kernel<<<dim3(NB, BB), 256, 0, stream>>>(qk, v, sticker, lse_tot, out, h);
}

// Round 2
// 503.289 us; speedup vs baseline: 3.5936x; 3.5936x over previous
//
#include <hip/hip_runtime.h>
#include <cstdint>
#include <cstddef>

#define BB 8
#define SS 8192
#define DD 64
#define HH 8
#define NB 128
#define NCHUNK 128   /* S / 64 */
#define CHUNKS 1024  /* H * NB */

typedef __attribute__((ext_vector_type(8))) short bf16x8;
typedef __attribute__((ext_vector_type(4))) float f32x4;

__device__ __forceinline__ unsigned short f2b(float x) {
  union { float f; unsigned int u; } c; c.f = x;
  unsigned int r = c.u + 0x7fffu + ((c.u >> 16) & 1u);
  return (unsigned short)(r >> 16);
}
__device__ __forceinline__ float b2f(unsigned short h) {
  union { unsigned int u; float f; } c; c.u = ((unsigned int)h) << 16;
  return c.f;
}

// ---------------------------------------------------------------------------
// Kernel 1: LSH hash (unchanged — exact f32 to keep argmax identical).
// ---------------------------------------------------------------------------
__global__ __launch_bounds__(256) void hash_kernel(const float* __restrict__ qk,
                                                   const float* __restrict__ rot,
                                                   unsigned char* __restrict__ bucket) {
  __shared__ float qs[64][68];
  __shared__ float rs[64][68];
  const int tid = threadIdx.x;
  const int b = blockIdx.y, tile = blockIdx.x;
  const int row = tid >> 2, part = tid & 3;

  {
    const float4* src = (const float4*)(qk + ((size_t)b * SS + (size_t)tile * 64 + row) * DD + part * 16);
    float* dst = &qs[row][part * 16];
#pragma unroll
    for (int k = 0; k < 4; ++k) {
      float4 f = src[k];
      dst[k * 4 + 0] = f.x; dst[k * 4 + 1] = f.y; dst[k * 4 + 2] = f.z; dst[k * 4 + 3] = f.w;
    }
  }

  for (int h = 0; h < HH; ++h) {
    __syncthreads();
    {
      const float4* src = (const float4*)(rot + (size_t)row * (HH * 64) + h * 64 + part * 16);
      float* dst = &rs[row][part * 16];
#pragma unroll
      for (int k = 0; k < 4; ++k) {
        float4 f = src[k];
        dst[k * 4 + 0] = f.x; dst[k * 4 + 1] = f.y; dst[k * 4 + 2] = f.z; dst[k * 4 + 3] = f.w;
      }
    }
    __syncthreads();

    const int t = row;
    float bestv = -3.4e38f;
    int besti = 0;
#pragma unroll
    for (int ii = 0; ii < 16; ++ii) {
      const int i = part * 16 + ii;
      float acc = 0.f;
#pragma unroll
      for (int f = 0; f < 64; ++f) acc += qs[t][f] * rs[f][i];
      if (acc > bestv || (acc == bestv && i < besti)) { bestv = acc; besti = i; }
      const float nv = -acc;
      if (nv > bestv || (nv == bestv && (i + 64) < besti)) { bestv = nv; besti = i + 64; }
    }
#pragma unroll
    for (int off = 1; off < 4; off <<= 1) {
      const float ov = __shfl_xor(bestv, off);
      const int oi = __shfl_xor(besti, off);
      if (ov > bestv || (ov == bestv && oi < besti)) { bestv = ov; besti = oi; }
    }
    if (part == 0)
      bucket[((size_t)(b * HH + h)) * SS + (size_t)tile * 64 + t] = (unsigned char)besti;
  }
}

// ---------------------------------------------------------------------------
// Kernel 2: stable counting sort per (b,h). Ballot-based in-chunk rank.
// Also emits the inverse permutation ipos[bh][t] = sorted position.
// ---------------------------------------------------------------------------
__global__ __launch_bounds__(256) void sort_kernel(const unsigned char* __restrict__ bucket,
                                                   int* __restrict__ sticker,
                                                   int* __restrict__ ipos) {
  __shared__ unsigned char lb[SS];
  __shared__ unsigned int hist[NB * NCHUNK];
  __shared__ unsigned int ssum[256];
  const int tid = threadIdx.x;
  const int bh = blockIdx.x;

  {
    const uint4* src = (const uint4*)(bucket + (size_t)bh * SS);
    uint4* dst = (uint4*)lb;
    dst[tid] = src[tid];
    dst[tid + 256] = src[tid + 256];
  }
#pragma unroll
  for (int k = 0; k < (NB * NCHUNK) / 256; ++k) hist[tid + k * 256] = 0u;
  __syncthreads();

  for (int t = tid; t < SS; t += 256)
    atomicAdd(&hist[(int)lb[t] * NCHUNK + (t >> 6)], 1u);
  __syncthreads();

  unsigned int segsum = 0u;
  const int base = tid * 64;
  for (int e = 0; e < 64; ++e) segsum += hist[base + e];
  ssum[tid] = segsum;
  __syncthreads();
  for (int off = 1; off < 256; off <<= 1) {
    const unsigned int vv = (tid >= off) ? ssum[tid - off] : 0u;
    __syncthreads();
    ssum[tid] += vv;
    __syncthreads();
  }
  unsigned int run = ssum[tid] - segsum;
  for (int e = 0; e < 64; ++e) {
    const unsigned int tv = hist[base + e];
    hist[base + e] = run;
    run += tv;
  }
  __syncthreads();

  // scatter: one wave per chunk, rank via 7-bit match-any ballot
  const int wid = tid >> 6, lane = tid & 63;
  for (int c = wid; c < NCHUNK; c += 4) {
    const int t = c * 64 + lane;
    const int bk = lb[t];
    unsigned long long mm = ~0ull;
#pragma unroll
    for (int bit = 0; bit < 7; ++bit) {
      const unsigned long long bal = __ballot((bk >> bit) & 1);
      mm &= ((bk >> bit) & 1) ? bal : ~bal;
    }
    const int rank = __popcll(mm & ((1ull << lane) - 1ull));
    const int pos = (int)hist[bk * NCHUNK + c] + rank;
    sticker[(size_t)bh * SS + pos] = t;
    ipos[(size_t)bh * SS + t] = pos;
  }
}

// ---------------------------------------------------------------------------
// Shared staging helper pattern (inlined in both kernels):
// gather 128 rows of qk by tks, normalize -> kb (bf16), raw first 64 -> qb.
// MFMA scores: S[64][128] = qb(raw) * kb^T, *0.125, masked by positions.
// ---------------------------------------------------------------------------

// Kernel 3: logits (lse per row per hash round). Grid (NB, HH, BB).
__global__ __launch_bounds__(256) void logits_kernel(const float* __restrict__ qk,
                                                     const int* __restrict__ sticker,
                                                     float* __restrict__ logits) {
  __shared__ __align__(16) unsigned short kb[128][72];
  __shared__ __align__(16) unsigned short qb[64][72];
  __shared__ int tks[128];
  const int tid = threadIdx.x;
  const int bin = blockIdx.x, h = blockIdx.y, b = blockIdx.z;
  const int prev = (h * NB + bin + CHUNKS - 1) & (CHUNKS - 1);
  const int ph = prev >> 7, pbin = prev & 127;

  if (tid < 128) {
    const int j = tid;
    const int src = (j < 64) ? ((b * HH + h) * SS + bin * 64 + j)
                             : ((b * HH + ph) * SS + pbin * 64 + (j - 64));
    tks[j] = sticker[src];
  }
  __syncthreads();

  {
    const int jrow = tid >> 1, half = tid & 1;
    const float4* src = (const float4*)(qk + ((size_t)b * SS + tks[jrow]) * DD + half * 32);
    float vals[32];
    float ssq = 0.f;
#pragma unroll
    for (int k = 0; k < 8; ++k) {
      float4 f = src[k];
      vals[k * 4 + 0] = f.x; vals[k * 4 + 1] = f.y; vals[k * 4 + 2] = f.z; vals[k * 4 + 3] = f.w;
      ssq += f.x * f.x + f.y * f.y + f.z * f.z + f.w * f.w;
    }
    ssq += __shfl_xor(ssq, 1);
    const float r = rsqrtf(ssq + 1e-6f);
    unsigned short* kd = &kb[jrow][half * 32];
#pragma unroll
    for (int m = 0; m < 32; ++m) kd[m] = f2b(vals[m] * r);
    if (jrow < 64) {
      unsigned short* qd = &qb[jrow][half * 32];
#pragma unroll
      for (int m = 0; m < 32; ++m) qd[m] = f2b(vals[m]);
    }
  }
  __syncthreads();

  const int lane = tid & 63, w = tid >> 6;
  const int r16 = lane & 15, g = lane >> 4;

  f32x4 acc[8];
#pragma unroll
  for (int n = 0; n < 8; ++n) acc[n] = (f32x4){0.f, 0.f, 0.f, 0.f};
  bf16x8 af0 = *(const bf16x8*)&qb[16 * w + r16][g * 8];
  bf16x8 af1 = *(const bf16x8*)&qb[16 * w + r16][32 + g * 8];
#pragma unroll
  for (int n = 0; n < 8; ++n) {
    bf16x8 bf0 = *(const bf16x8*)&kb[16 * n + r16][g * 8];
    bf16x8 bf1 = *(const bf16x8*)&kb[16 * n + r16][32 + g * 8];
    acc[n] = __builtin_amdgcn_mfma_f32_16x16x32_bf16(af0, bf0, acc[n], 0, 0, 0);
    acc[n] = __builtin_amdgcn_mfma_f32_16x16x32_bf16(af1, bf1, acc[n], 0, 0, 0);
  }

  int tkj[8];
#pragma unroll
  for (int n = 0; n < 8; ++n) tkj[n] = tks[16 * n + r16];

  float res[4];
  int tqs[4];
#pragma unroll
  for (int i = 0; i < 4; ++i) {
    const int tq = tks[16 * w + 4 * g + i];
    tqs[i] = tq;
    float dv[8];
    float mm = -3.4e38f;
#pragma unroll
    for (int n = 0; n < 8; ++n) {
      float s = acc[n][i] * 0.125f;
      s = (tkj[n] > tq) ? -1e38f : ((tkj[n] == tq) ? -50000.f : s);
      dv[n] = s;
      mm = fmaxf(mm, s);
    }
    mm = fmaxf(mm, __shfl_xor(mm, 1));
    mm = fmaxf(mm, __shfl_xor(mm, 2));
    mm = fmaxf(mm, __shfl_xor(mm, 4));
    mm = fmaxf(mm, __shfl_xor(mm, 8));
    float sum = 0.f;
#pragma unroll
    for (int n = 0; n < 8; ++n) sum += __expf(dv[n] - mm);
    sum += __shfl_xor(sum, 1);
    sum += __shfl_xor(sum, 2);
    sum += __shfl_xor(sum, 4);
    sum += __shfl_xor(sum, 8);
    res[i] = mm + logf(sum);
  }
  if (r16 == 0) {
#pragma unroll
    for (int i = 0; i < 4; ++i)
      logits[((size_t)(b * HH + h)) * SS + tqs[i]] = res[i];
  }
}

// ---------------------------------------------------------------------------
// Kernel 4: LSE over hash rounds per (b,t).
// ---------------------------------------------------------------------------
__global__ __launch_bounds__(256) void combine_lse_kernel(const float* __restrict__ logits,
                                                          float* __restrict__ lse_tot) {
  const int idx = blockIdx.x * 256 + threadIdx.x;
  const int b = idx >> 13, t = idx & (SS - 1);
  float l[HH];
  float m = -3.4e38f;
#pragma unroll
  for (int h = 0; h < HH; ++h) {
    l[h] = logits[((size_t)(b * HH + h)) * SS + t];
    m = fmaxf(m, l[h]);
  }
  float sum = 0.f;
#pragma unroll
  for (int h = 0; h < HH; ++h) sum += __expf(l[h] - m);
  lse_tot[idx] = m + logf(sum);
}

// ---------------------------------------------------------------------------
// Kernel 5: attention. hfix < 0: grid (NB, BB, HH), write weighted bf16
// contributions to `so` in sorted order (race-free). hfix >= 0: grid
// (NB, BB), accumulate into out (serialized per-h launches).
// ---------------------------------------------------------------------------
__global__ __launch_bounds__(256) void attn_kernel(const float* __restrict__ qk,
                                                   const float* __restrict__ v,
                                                   const int* __restrict__ sticker,
                                                   const float* __restrict__ lse_tot,
                                                   unsigned short* __restrict__ so,
                                                   float* __restrict__ out,
                                                   const int hfix) {
  __shared__ __align__(16) unsigned short kb[128][72];
  __shared__ __align__(16) unsigned short qb[64][72];
  __shared__ __align__(16) unsigned short vt[64][136];
  __shared__ __align__(16) unsigned short ps[64][136];
  __shared__ int tks[128];
  __shared__ float lseq[64];
  const int tid = threadIdx.x;
  const int bin = blockIdx.x, b = blockIdx.y;
  const int h = (hfix < 0) ? blockIdx.z : hfix;
  const int prev = (h * NB + bin + CHUNKS - 1) & (CHUNKS - 1);
  const int ph = prev >> 7, pbin = prev & 127;

  if (tid < 128) {
    const int j = tid;
    const int src = (j < 64) ? ((b * HH + h) * SS + bin * 64 + j)
                             : ((b * HH + ph) * SS + pbin * 64 + (j - 64));
    tks[j] = sticker[src];
  }
  __syncthreads();

  {
    const int jrow = tid >> 1, half = tid & 1;
    const int trow = tks[jrow];
    {
      const float4* src = (const float4*)(qk + ((size_t)b * SS + trow) * DD + half * 32);
      float vals[32];
      float ssq = 0.f;
#pragma unroll
      for (int k = 0; k < 8; ++k) {
        float4 f = src[k];
        vals[k * 4 + 0] = f.x; vals[k * 4 + 1] = f.y; vals[k * 4 + 2] = f.z; vals[k * 4 + 3] = f.w;
        ssq += f.x * f.x + f.y * f.y + f.z * f.z + f.w * f.w;
      }
      ssq += __shfl_xor(ssq, 1);
      const float r = rsqrtf(ssq + 1e-6f);
      unsigned short* kd = &kb[jrow][half * 32];
#pragma unroll
      for (int m = 0; m < 32; ++m) kd[m] = f2b(vals[m] * r);
      if (jrow < 64) {
        unsigned short* qd = &qb[jrow][half * 32];
#pragma unroll
        for (int m = 0; m < 32; ++m) qd[m] = f2b(vals[m]);
      }
    }
    {
      const float4* vsrc = (const float4*)(v + ((size_t)b * SS + trow) * DD + half * 32);
#pragma unroll
      for (int k = 0; k < 8; ++k) {
        float4 f = vsrc[k];
        const int d0 = half * 32 + k * 4;
        vt[d0 + 0][jrow] = f2b(f.x);
        vt[d0 + 1][jrow] = f2b(f.y);
        vt[d0 + 2][jrow] = f2b(f.z);
        vt[d0 + 3][jrow] = f2b(f.w);
      }
    }
  }
  if (tid < 64) lseq[tid] = lse_tot[b * SS + tks[tid]];
  __syncthreads();

  const int lane = tid & 63, w = tid >> 6;
  const int r16 = lane & 15, g = lane >> 4;

  f32x4 acc[8];
#pragma unroll
  for (int n = 0; n < 8; ++n) acc[n] = (f32x4){0.f, 0.f, 0.f, 0.f};
  bf16x8 af0 = *(const bf16x8*)&qb[16 * w + r16][g * 8];
  bf16x8 af1 = *(const bf16x8*)&qb[16 * w + r16][32 + g * 8];
#pragma unroll
  for (int n = 0; n < 8; ++n) {
    bf16x8 bf0 = *(const bf16x8*)&kb[16 * n + r16][g * 8];
    bf16x8 bf1 = *(const bf16x8*)&kb[16 * n + r16][32 + g * 8];
    acc[n] = __builtin_amdgcn_mfma_f32_16x16x32_bf16(af0, bf0, acc[n], 0, 0, 0);
    acc[n] = __builtin_amdgcn_mfma_f32_16x16x32_bf16(af1, bf1, acc[n], 0, 0, 0);
  }

  int tkj[8];
#pragma unroll
  for (int n = 0; n < 8; ++n) tkj[n] = tks[16 * n + r16];

#pragma unroll
  for (int i = 0; i < 4; ++i) {
    const int q = 16 * w + 4 * g + i;
    const int tq = tks[q];
    const float lse = lseq[q];
#pragma unroll
    for (int n = 0; n < 8; ++n) {
      float s = acc[n][i] * 0.125f;
      float p;
      if (tkj[n] > tq) p = 0.f;
      else p = __expf(((tkj[n] == tq) ? -50000.f : s) - lse);
      ps[q][16 * n + r16] = f2b(p);
    }
  }
  __syncthreads();

  f32x4 o[4];
#pragma unroll
  for (int n = 0; n < 4; ++n) o[n] = (f32x4){0.f, 0.f, 0.f, 0.f};
#pragma unroll
  for (int kk = 0; kk < 4; ++kk) {
    bf16x8 pa = *(const bf16x8*)&ps[16 * w + r16][kk * 32 + g * 8];
#pragma unroll
    for (int n = 0; n < 4; ++n) {
      bf16x8 vb = *(const bf16x8*)&vt[16 * n + r16][kk * 32 + g * 8];
      o[n] = __builtin_amdgcn_mfma_f32_16x16x32_bf16(pa, vb, o[n], 0, 0, 0);
    }
  }

  if (hfix < 0) {
    unsigned short* dst = so + ((size_t)((b * HH + h)) * SS + (size_t)bin * 64) * DD;
#pragma unroll
    for (int i = 0; i < 4; ++i) {
      const int q = 16 * w + 4 * g + i;
#pragma unroll
      for (int n = 0; n < 4; ++n)
        dst[q * DD + 16 * n + r16] = f2b(o[n][i]);
    }
  } else {
#pragma unroll
    for (int i = 0; i < 4; ++i) {
      const int q = 16 * w + 4 * g + i;
      float* orow = out + ((size_t)b * SS + tks[q]) * DD;
#pragma unroll
      for (int n = 0; n < 4; ++n)
        orow[16 * n + r16] += o[n][i];
    }
  }
}

// ---------------------------------------------------------------------------
// Kernel 6: final combine — out[b,t] = sum_h so[b,h,ipos(h,t)].
// ---------------------------------------------------------------------------
__global__ __launch_bounds__(256) void gather_out_kernel(const unsigned short* __restrict__ so,
                                                         const int* __restrict__ ipos,
                                                         float* __restrict__ out) {
  const int idx = blockIdx.x * 256 + threadIdx.x;  // (b, t, quarter)
  const int quarter = idx & 3;
  const int bt = idx >> 2;
  const int b = bt >> 13, t = bt & (SS - 1);
  float acc[16];
#pragma unroll
  for (int k = 0; k < 16; ++k) acc[k] = 0.f;
#pragma unroll
  for (int h = 0; h < HH; ++h) {
    const int pos = ipos[((size_t)(b * HH + h)) * SS + t];
    const unsigned short* row = so + (((size_t)(b * HH + h)) * SS + pos) * DD + quarter * 16;
    unsigned short vals[16];
    *(uint4*)&vals[0] = *(const uint4*)&row[0];
    *(uint4*)&vals[8] = *(const uint4*)&row[8];
#pragma unroll
    for (int k = 0; k < 16; ++k) acc[k] += b2f(vals[k]);
  }
  float* dst = out + ((size_t)b * SS + t) * DD + quarter * 16;
#pragma unroll
  for (int wq = 0; wq < 4; ++wq) {
    float4 ov;
    ov.x = acc[wq * 4 + 0]; ov.y = acc[wq * 4 + 1];
    ov.z = acc[wq * 4 + 2]; ov.w = acc[wq * 4 + 3];
    ((float4*)dst)[wq] = ov;
  }
}

// ---------------------------------------------------------------------------
extern "C" void kernel_launch(void* const* d_in, const int* in_sizes, int n_in,
                              void* d_out, int out_size, void* d_ws, size_t ws_size,
                              hipStream_t stream) {
  (void)in_sizes; (void)n_in; (void)out_size;
  const float* qk = (const float*)d_in[0];
  const float* v = (const float*)d_in[1];
  const float* rot = (const float*)d_in[2];
  float* out = (float*)d_out;

  char* ws = (char*)d_ws;
  int* sticker = (int*)ws;                                       // 2 MB
  int* ipos = (int*)(ws + ((size_t)2 << 20));                    // 2 MB
  float* logits = (float*)(ws + ((size_t)4 << 20));              // 2 MB
  float* lse_tot = (float*)(ws + ((size_t)6 << 20));             // 256 KB
  unsigned char* bucket = (unsigned char*)(ws + ((size_t)6 << 20) + ((size_t)256 << 10));  // 512 KB
  unsigned short* so = (unsigned short*)(ws + ((size_t)8 << 20)); // 64 MB (fast path)
  const size_t need_fast = ((size_t)8 << 20) + (size_t)BB * HH * SS * DD * 2;
  const bool fast = ws_size >= need_fast;

  hash_kernel<<<dim3(NCHUNK, BB), 256, 0, stream>>>(qk, rot, bucket);
  sort_kernel<<<BB * HH, 256, 0, stream>>>(bucket, sticker, ipos);
  logits_kernel<<<dim3(NB, HH, BB), 256, 0, stream>>>(qk, sticker, logits);
  combine_lse_kernel<<<(BB * SS) / 256, 256, 0, stream>>>(logits, lse_tot);

  if (fast) {
    attn_kernel<<<dim3(NB, BB, HH), 256, 0, stream>>>(qk, v, sticker, lse_tot, so, nullptr, -1);
    gather_out_kernel<<<(BB * SS * 4) / 256, 256, 0, stream>>>(so, ipos, out);
  } else {
    hipMemsetAsync(d_out, 0, (size_t)BB * SS * DD * sizeof(float), stream);
    for (int h = 0; h < HH; ++h)
      attn_kernel<<<dim3(NB, BB), 256, 0, stream>>>(qk, v, sticker, lse_tot, nullptr, out, h);
  }
}

// Round 3
// 293.001 us; speedup vs baseline: 6.1727x; 1.7177x over previous
//
#include <hip/hip_runtime.h>
#include <cstdint>
#include <cstddef>

#define BB 8
#define SS 8192
#define DD 64
#define HH 8
#define NB 128
#define NCHUNK 128   /* S / 64 */
#define CHUNKS 1024  /* H * NB */

typedef __attribute__((ext_vector_type(8))) short bf16x8;
typedef __attribute__((ext_vector_type(4))) float f32x4;

__device__ __forceinline__ unsigned short f2b(float x) {
  union { float f; unsigned int u; } c; c.f = x;
  unsigned int r = c.u + 0x7fffu + ((c.u >> 16) & 1u);
  return (unsigned short)(r >> 16);
}
__device__ __forceinline__ float b2f(unsigned short h) {
  union { unsigned int u; float f; } c; c.u = ((unsigned int)h) << 16;
  return c.f;
}

// ---------------------------------------------------------------------------
// Kernel 1: LSH hash, register-tiled f32 (bitwise-identical dot products to
// the naive version: serial f=0..63 fmac chain). Grid (NCHUNK, BB), 256 thr.
// Wave w: hbuf = w>>1 (two h's staged per phase), rows 32*(w&1)..+31.
// Thread tile: 4 rows x 8 cols. qsT[f][t] transposed so row-reads are b128.
// ---------------------------------------------------------------------------
__global__ __launch_bounds__(256) void hash_kernel(const float* __restrict__ qk,
                                                   const float* __restrict__ rot,
                                                   unsigned char* __restrict__ bucket) {
  __shared__ __align__(16) float qsT[64][68];
  __shared__ __align__(16) float rs[2][64][68];
  const int tid = threadIdx.x;
  const int b = blockIdx.y, tile = blockIdx.x;

  // stage qsT (transposed): thread loads 16 consecutive f of row t
  {
    const int t = tid >> 2, part = tid & 3;
    const float4* src = (const float4*)(qk + ((size_t)b * SS + (size_t)tile * 64 + t) * DD + part * 16);
    float vals[16];
#pragma unroll
    for (int k = 0; k < 4; ++k) {
      float4 f = src[k];
      vals[k * 4 + 0] = f.x; vals[k * 4 + 1] = f.y; vals[k * 4 + 2] = f.z; vals[k * 4 + 3] = f.w;
    }
#pragma unroll
    for (int k = 0; k < 16; ++k) qsT[part * 16 + k][t] = vals[k];
  }

  const int w = tid >> 6, lane = tid & 63;
  const int tx = lane & 7, ty = lane >> 3;
  const int hbuf = w >> 1;
  const int rowbase = 32 * (w & 1);

  for (int hp = 0; hp < 4; ++hp) {
    __syncthreads();  // previous compute done (and qsT ready on first iter)
    // stage rs[0] <- h=2hp, rs[1] <- h=2hp+1 (8192 floats, 32 per thread)
    {
#pragma unroll
      for (int rep = 0; rep < 32; ++rep) {
        const int flat = rep * 256 + tid;
        const int hb = flat >> 12, f = (flat >> 6) & 63, i = flat & 63;
        rs[hb][f][i] = rot[(size_t)f * (HH * 64) + (2 * hp + hb) * 64 + i];
      }
    }
    __syncthreads();

    const int h = 2 * hp + hbuf;
    float acc[4][8];
#pragma unroll
    for (int r = 0; r < 4; ++r)
#pragma unroll
      for (int c = 0; c < 8; ++c) acc[r][c] = 0.f;

#pragma unroll 8
    for (int f = 0; f < 64; ++f) {
      const float4 qv = *(const float4*)&qsT[f][rowbase + 4 * ty];
      const float4 rv0 = *(const float4*)&rs[hbuf][f][8 * tx];
      const float4 rv1 = *(const float4*)&rs[hbuf][f][8 * tx + 4];
      const float qr[4] = {qv.x, qv.y, qv.z, qv.w};
      const float rc[8] = {rv0.x, rv0.y, rv0.z, rv0.w, rv1.x, rv1.y, rv1.z, rv1.w};
#pragma unroll
      for (int r = 0; r < 4; ++r)
#pragma unroll
        for (int c = 0; c < 8; ++c) acc[r][c] += qr[r] * rc[c];
    }

    // per-row argmax over [rot, -rot] (idx < 64 pos, idx+64 neg), then
    // reduce across the 8 tx lanes. Tie rule: greater value, then lower idx.
    unsigned int pack = 0;
#pragma unroll
    for (int r = 0; r < 4; ++r) {
      float bv = -3.4e38f;
      int bi = 0;
#pragma unroll
      for (int c = 0; c < 8; ++c) {
        const int i = 8 * tx + c;
        const float vp = acc[r][c];
        if (vp > bv || (vp == bv && i < bi)) { bv = vp; bi = i; }
        const float vn = -vp;
        if (vn > bv || (vn == bv && (i + 64) < bi)) { bv = vn; bi = i + 64; }
      }
#pragma unroll
      for (int off = 1; off < 8; off <<= 1) {
        const float ov = __shfl_xor(bv, off);
        const int oi = __shfl_xor(bi, off);
        if (ov > bv || (ov == bv && oi < bi)) { bv = ov; bi = oi; }
      }
      pack |= ((unsigned int)bi) << (8 * r);
    }
    if (tx == 0) {
      *(unsigned int*)&bucket[((size_t)(b * HH + h)) * SS + (size_t)tile * 64 + rowbase + 4 * ty] = pack;
    }
  }
}

// ---------------------------------------------------------------------------
// Kernel 2: stable counting sort per (b,h). Ballot-based in-chunk rank.
// Also emits the inverse permutation ipos[bh][t] = sorted position.
// ---------------------------------------------------------------------------
__global__ __launch_bounds__(256) void sort_kernel(const unsigned char* __restrict__ bucket,
                                                   int* __restrict__ sticker,
                                                   int* __restrict__ ipos) {
  __shared__ unsigned char lb[SS];
  __shared__ unsigned int hist[NB * NCHUNK];
  __shared__ unsigned int ssum[256];
  const int tid = threadIdx.x;
  const int bh = blockIdx.x;

  {
    const uint4* src = (const uint4*)(bucket + (size_t)bh * SS);
    uint4* dst = (uint4*)lb;
    dst[tid] = src[tid];
    dst[tid + 256] = src[tid + 256];
  }
#pragma unroll
  for (int k = 0; k < (NB * NCHUNK) / 256; ++k) hist[tid + k * 256] = 0u;
  __syncthreads();

  for (int t = tid; t < SS; t += 256)
    atomicAdd(&hist[(int)lb[t] * NCHUNK + (t >> 6)], 1u);
  __syncthreads();

  unsigned int segsum = 0u;
  const int base = tid * 64;
  for (int e = 0; e < 64; ++e) segsum += hist[base + e];
  ssum[tid] = segsum;
  __syncthreads();
  for (int off = 1; off < 256; off <<= 1) {
    const unsigned int vv = (tid >= off) ? ssum[tid - off] : 0u;
    __syncthreads();
    ssum[tid] += vv;
    __syncthreads();
  }
  unsigned int run = ssum[tid] - segsum;
  for (int e = 0; e < 64; ++e) {
    const unsigned int tv = hist[base + e];
    hist[base + e] = run;
    run += tv;
  }
  __syncthreads();

  // scatter: one wave per chunk, rank via 7-bit match-any ballot
  const int wid = tid >> 6, lane = tid & 63;
  for (int c = wid; c < NCHUNK; c += 4) {
    const int t = c * 64 + lane;
    const int bk = lb[t];
    unsigned long long mm = ~0ull;
#pragma unroll
    for (int bit = 0; bit < 7; ++bit) {
      const unsigned long long bal = __ballot((bk >> bit) & 1);
      mm &= ((bk >> bit) & 1) ? bal : ~bal;
    }
    const int rank = __popcll(mm & ((1ull << lane) - 1ull));
    const int pos = (int)hist[bk * NCHUNK + c] + rank;
    sticker[(size_t)bh * SS + pos] = t;
    ipos[(size_t)bh * SS + t] = pos;
  }
}

// ---------------------------------------------------------------------------
// Kernel 3: logits (lse per row per hash round). Grid (NB, HH, BB).
// ---------------------------------------------------------------------------
__global__ __launch_bounds__(256) void logits_kernel(const float* __restrict__ qk,
                                                     const int* __restrict__ sticker,
                                                     float* __restrict__ logits) {
  __shared__ __align__(16) unsigned short kb[128][72];
  __shared__ __align__(16) unsigned short qb[64][72];
  __shared__ int tks[128];
  const int tid = threadIdx.x;
  const int bin = blockIdx.x, h = blockIdx.y, b = blockIdx.z;
  const int prev = (h * NB + bin + CHUNKS - 1) & (CHUNKS - 1);
  const int ph = prev >> 7, pbin = prev & 127;

  if (tid < 128) {
    const int j = tid;
    const int src = (j < 64) ? ((b * HH + h) * SS + bin * 64 + j)
                             : ((b * HH + ph) * SS + pbin * 64 + (j - 64));
    tks[j] = sticker[src];
  }
  __syncthreads();

  {
    const int jrow = tid >> 1, half = tid & 1;
    const float4* src = (const float4*)(qk + ((size_t)b * SS + tks[jrow]) * DD + half * 32);
    float vals[32];
    float ssq = 0.f;
#pragma unroll
    for (int k = 0; k < 8; ++k) {
      float4 f = src[k];
      vals[k * 4 + 0] = f.x; vals[k * 4 + 1] = f.y; vals[k * 4 + 2] = f.z; vals[k * 4 + 3] = f.w;
      ssq += f.x * f.x + f.y * f.y + f.z * f.z + f.w * f.w;
    }
    ssq += __shfl_xor(ssq, 1);
    const float r = rsqrtf(ssq + 1e-6f);
    unsigned short* kd = &kb[jrow][half * 32];
#pragma unroll
    for (int m = 0; m < 32; ++m) kd[m] = f2b(vals[m] * r);
    if (jrow < 64) {
      unsigned short* qd = &qb[jrow][half * 32];
#pragma unroll
      for (int m = 0; m < 32; ++m) qd[m] = f2b(vals[m]);
    }
  }
  __syncthreads();

  const int lane = tid & 63, w = tid >> 6;
  const int r16 = lane & 15, g = lane >> 4;

  f32x4 acc[8];
#pragma unroll
  for (int n = 0; n < 8; ++n) acc[n] = (f32x4){0.f, 0.f, 0.f, 0.f};
  bf16x8 af0 = *(const bf16x8*)&qb[16 * w + r16][g * 8];
  bf16x8 af1 = *(const bf16x8*)&qb[16 * w + r16][32 + g * 8];
#pragma unroll
  for (int n = 0; n < 8; ++n) {
    bf16x8 bf0 = *(const bf16x8*)&kb[16 * n + r16][g * 8];
    bf16x8 bf1 = *(const bf16x8*)&kb[16 * n + r16][32 + g * 8];
    acc[n] = __builtin_amdgcn_mfma_f32_16x16x32_bf16(af0, bf0, acc[n], 0, 0, 0);
    acc[n] = __builtin_amdgcn_mfma_f32_16x16x32_bf16(af1, bf1, acc[n], 0, 0, 0);
  }

  int tkj[8];
#pragma unroll
  for (int n = 0; n < 8; ++n) tkj[n] = tks[16 * n + r16];

  float res[4];
  int tqs[4];
#pragma unroll
  for (int i = 0; i < 4; ++i) {
    const int tq = tks[16 * w + 4 * g + i];
    tqs[i] = tq;
    float dv[8];
    float mm = -3.4e38f;
#pragma unroll
    for (int n = 0; n < 8; ++n) {
      float s = acc[n][i] * 0.125f;
      s = (tkj[n] > tq) ? -1e38f : ((tkj[n] == tq) ? -50000.f : s);
      dv[n] = s;
      mm = fmaxf(mm, s);
    }
    mm = fmaxf(mm, __shfl_xor(mm, 1));
    mm = fmaxf(mm, __shfl_xor(mm, 2));
    mm = fmaxf(mm, __shfl_xor(mm, 4));
    mm = fmaxf(mm, __shfl_xor(mm, 8));
    float sum = 0.f;
#pragma unroll
    for (int n = 0; n < 8; ++n) sum += __expf(dv[n] - mm);
    sum += __shfl_xor(sum, 1);
    sum += __shfl_xor(sum, 2);
    sum += __shfl_xor(sum, 4);
    sum += __shfl_xor(sum, 8);
    res[i] = mm + logf(sum);
  }
  if (r16 == 0) {
#pragma unroll
    for (int i = 0; i < 4; ++i)
      logits[((size_t)(b * HH + h)) * SS + tqs[i]] = res[i];
  }
}

// ---------------------------------------------------------------------------
// Kernel 4: LSE over hash rounds per (b,t).
// ---------------------------------------------------------------------------
__global__ __launch_bounds__(256) void combine_lse_kernel(const float* __restrict__ logits,
                                                          float* __restrict__ lse_tot) {
  const int idx = blockIdx.x * 256 + threadIdx.x;
  const int b = idx >> 13, t = idx & (SS - 1);
  float l[HH];
  float m = -3.4e38f;
#pragma unroll
  for (int h = 0; h < HH; ++h) {
    l[h] = logits[((size_t)(b * HH + h)) * SS + t];
    m = fmaxf(m, l[h]);
  }
  float sum = 0.f;
#pragma unroll
  for (int h = 0; h < HH; ++h) sum += __expf(l[h] - m);
  lse_tot[idx] = m + logf(sum);
}

// ---------------------------------------------------------------------------
// Kernel 5: attention. hfix < 0: grid (NB, BB, HH), write weighted bf16
// contributions to `so` in sorted order (race-free). hfix >= 0: grid
// (NB, BB), accumulate into out (serialized per-h launches).
// ---------------------------------------------------------------------------
__global__ __launch_bounds__(256) void attn_kernel(const float* __restrict__ qk,
                                                   const float* __restrict__ v,
                                                   const int* __restrict__ sticker,
                                                   const float* __restrict__ lse_tot,
                                                   unsigned short* __restrict__ so,
                                                   float* __restrict__ out,
                                                   const int hfix) {
  __shared__ __align__(16) unsigned short kb[128][72];
  __shared__ __align__(16) unsigned short qb[64][72];
  __shared__ __align__(16) unsigned short vt[64][136];
  __shared__ __align__(16) unsigned short ps[64][136];
  __shared__ int tks[128];
  __shared__ float lseq[64];
  const int tid = threadIdx.x;
  const int bin = blockIdx.x, b = blockIdx.y;
  const int h = (hfix < 0) ? blockIdx.z : hfix;
  const int prev = (h * NB + bin + CHUNKS - 1) & (CHUNKS - 1);
  const int ph = prev >> 7, pbin = prev & 127;

  if (tid < 128) {
    const int j = tid;
    const int src = (j < 64) ? ((b * HH + h) * SS + bin * 64 + j)
                             : ((b * HH + ph) * SS + pbin * 64 + (j - 64));
    tks[j] = sticker[src];
  }
  __syncthreads();

  {
    const int jrow = tid >> 1, half = tid & 1;
    const int trow = tks[jrow];
    {
      const float4* src = (const float4*)(qk + ((size_t)b * SS + trow) * DD + half * 32);
      float vals[32];
      float ssq = 0.f;
#pragma unroll
      for (int k = 0; k < 8; ++k) {
        float4 f = src[k];
        vals[k * 4 + 0] = f.x; vals[k * 4 + 1] = f.y; vals[k * 4 + 2] = f.z; vals[k * 4 + 3] = f.w;
        ssq += f.x * f.x + f.y * f.y + f.z * f.z + f.w * f.w;
      }
      ssq += __shfl_xor(ssq, 1);
      const float r = rsqrtf(ssq + 1e-6f);
      unsigned short* kd = &kb[jrow][half * 32];
#pragma unroll
      for (int m = 0; m < 32; ++m) kd[m] = f2b(vals[m] * r);
      if (jrow < 64) {
        unsigned short* qd = &qb[jrow][half * 32];
#pragma unroll
        for (int m = 0; m < 32; ++m) qd[m] = f2b(vals[m]);
      }
    }
    {
      const float4* vsrc = (const float4*)(v + ((size_t)b * SS + trow) * DD + half * 32);
#pragma unroll
      for (int k = 0; k < 8; ++k) {
        float4 f = vsrc[k];
        const int d0 = half * 32 + k * 4;
        vt[d0 + 0][jrow] = f2b(f.x);
        vt[d0 + 1][jrow] = f2b(f.y);
        vt[d0 + 2][jrow] = f2b(f.z);
        vt[d0 + 3][jrow] = f2b(f.w);
      }
    }
  }
  if (tid < 64) lseq[tid] = lse_tot[b * SS + tks[tid]];
  __syncthreads();

  const int lane = tid & 63, w = tid >> 6;
  const int r16 = lane & 15, g = lane >> 4;

  f32x4 acc[8];
#pragma unroll
  for (int n = 0; n < 8; ++n) acc[n] = (f32x4){0.f, 0.f, 0.f, 0.f};
  bf16x8 af0 = *(const bf16x8*)&qb[16 * w + r16][g * 8];
  bf16x8 af1 = *(const bf16x8*)&qb[16 * w + r16][32 + g * 8];
#pragma unroll
  for (int n = 0; n < 8; ++n) {
    bf16x8 bf0 = *(const bf16x8*)&kb[16 * n + r16][g * 8];
    bf16x8 bf1 = *(const bf16x8*)&kb[16 * n + r16][32 + g * 8];
    acc[n] = __builtin_amdgcn_mfma_f32_16x16x32_bf16(af0, bf0, acc[n], 0, 0, 0);
    acc[n] = __builtin_amdgcn_mfma_f32_16x16x32_bf16(af1, bf1, acc[n], 0, 0, 0);
  }

  int tkj[8];
#pragma unroll
  for (int n = 0; n < 8; ++n) tkj[n] = tks[16 * n + r16];

#pragma unroll
  for (int i = 0; i < 4; ++i) {
    const int q = 16 * w + 4 * g + i;
    const int tq = tks[q];
    const float lse = lseq[q];
#pragma unroll
    for (int n = 0; n < 8; ++n) {
      float s = acc[n][i] * 0.125f;
      float p;
      if (tkj[n] > tq) p = 0.f;
      else p = __expf(((tkj[n] == tq) ? -50000.f : s) - lse);
      ps[q][16 * n + r16] = f2b(p);
    }
  }
  __syncthreads();

  f32x4 o[4];
#pragma unroll
  for (int n = 0; n < 4; ++n) o[n] = (f32x4){0.f, 0.f, 0.f, 0.f};
#pragma unroll
  for (int kk = 0; kk < 4; ++kk) {
    bf16x8 pa = *(const bf16x8*)&ps[16 * w + r16][kk * 32 + g * 8];
#pragma unroll
    for (int n = 0; n < 4; ++n) {
      bf16x8 vb = *(const bf16x8*)&vt[16 * n + r16][kk * 32 + g * 8];
      o[n] = __builtin_amdgcn_mfma_f32_16x16x32_bf16(pa, vb, o[n], 0, 0, 0);
    }
  }

  if (hfix < 0) {
    unsigned short* dst = so + ((size_t)((b * HH + h)) * SS + (size_t)bin * 64) * DD;
#pragma unroll
    for (int i = 0; i < 4; ++i) {
      const int q = 16 * w + 4 * g + i;
#pragma unroll
      for (int n = 0; n < 4; ++n)
        dst[q * DD + 16 * n + r16] = f2b(o[n][i]);
    }
  } else {
#pragma unroll
    for (int i = 0; i < 4; ++i) {
      const int q = 16 * w + 4 * g + i;
      float* orow = out + ((size_t)b * SS + tks[q]) * DD;
#pragma unroll
      for (int n = 0; n < 4; ++n)
        orow[16 * n + r16] += o[n][i];
    }
  }
}

// ---------------------------------------------------------------------------
// Kernel 6: final combine — out[b,t] = sum_h so[b,h,ipos(h,t)].
// ---------------------------------------------------------------------------
__global__ __launch_bounds__(256) void gather_out_kernel(const unsigned short* __restrict__ so,
                                                         const int* __restrict__ ipos,
                                                         float* __restrict__ out) {
  const int idx = blockIdx.x * 256 + threadIdx.x;  // (b, t, quarter)
  const int quarter = idx & 3;
  const int bt = idx >> 2;
  const int b = bt >> 13, t = bt & (SS - 1);
  float acc[16];
#pragma unroll
  for (int k = 0; k < 16; ++k) acc[k] = 0.f;
#pragma unroll
  for (int h = 0; h < HH; ++h) {
    const int pos = ipos[((size_t)(b * HH + h)) * SS + t];
    const unsigned short* row = so + (((size_t)(b * HH + h)) * SS + pos) * DD + quarter * 16;
    unsigned short vals[16];
    *(uint4*)&vals[0] = *(const uint4*)&row[0];
    *(uint4*)&vals[8] = *(const uint4*)&row[8];
#pragma unroll
    for (int k = 0; k < 16; ++k) acc[k] += b2f(vals[k]);
  }
  float* dst = out + ((size_t)b * SS + t) * DD + quarter * 16;
#pragma unroll
  for (int wq = 0; wq < 4; ++wq) {
    float4 ov;
    ov.x = acc[wq * 4 + 0]; ov.y = acc[wq * 4 + 1];
    ov.z = acc[wq * 4 + 2]; ov.w = acc[wq * 4 + 3];
    ((float4*)dst)[wq] = ov;
  }
}

// ---------------------------------------------------------------------------
extern "C" void kernel_launch(void* const* d_in, const int* in_sizes, int n_in,
                              void* d_out, int out_size, void* d_ws, size_t ws_size,
                              hipStream_t stream) {
  (void)in_sizes; (void)n_in; (void)out_size;
  const float* qk = (const float*)d_in[0];
  const float* v = (const float*)d_in[1];
  const float* rot = (const float*)d_in[2];
  float* out = (float*)d_out;

  char* ws = (char*)d_ws;
  int* sticker = (int*)ws;                                       // 2 MB
  int* ipos = (int*)(ws + ((size_t)2 << 20));                    // 2 MB
  float* logits = (float*)(ws + ((size_t)4 << 20));              // 2 MB
  float* lse_tot = (float*)(ws + ((size_t)6 << 20));             // 256 KB
  unsigned char* bucket = (unsigned char*)(ws + ((size_t)6 << 20) + ((size_t)256 << 10));  // 512 KB
  unsigned short* so = (unsigned short*)(ws + ((size_t)8 << 20)); // 64 MB (fast path)
  const size_t need_fast = ((size_t)8 << 20) + (size_t)BB * HH * SS * DD * 2;
  const bool fast = ws_size >= need_fast;

  hash_kernel<<<dim3(NCHUNK, BB), 256, 0, stream>>>(qk, rot, bucket);
  sort_kernel<<<BB * HH, 256, 0, stream>>>(bucket, sticker, ipos);
  logits_kernel<<<dim3(NB, HH, BB), 256, 0, stream>>>(qk, sticker, logits);
  combine_lse_kernel<<<(BB * SS) / 256, 256, 0, stream>>>(logits, lse_tot);

  if (fast) {
    attn_kernel<<<dim3(NB, BB, HH), 256, 0, stream>>>(qk, v, sticker, lse_tot, so, nullptr, -1);
    gather_out_kernel<<<(BB * SS * 4) / 256, 256, 0, stream>>>(so, ipos, out);
  } else {
    hipMemsetAsync(d_out, 0, (size_t)BB * SS * DD * sizeof(float), stream);
    for (int h = 0; h < HH; ++h)
      attn_kernel<<<dim3(NB, BB), 256, 0, stream>>>(qk, v, sticker, lse_tot, nullptr, out, h);
  }
}

// Round 4
// 224.811 us; speedup vs baseline: 8.0451x; 1.3033x over previous
//
#include <hip/hip_runtime.h>
#include <cstdint>
#include <cstddef>

#define BB 8
#define SS 8192
#define DD 64
#define HH 8
#define NB 128
#define NCHUNK 128   /* S / 64 */
#define CHUNKS 1024  /* H * NB */

typedef __attribute__((ext_vector_type(8))) short bf16x8;
typedef __attribute__((ext_vector_type(4))) float f32x4;

__device__ __forceinline__ unsigned short f2b(float x) {
  union { float f; unsigned int u; } c; c.f = x;
  unsigned int r = c.u + 0x7fffu + ((c.u >> 16) & 1u);
  return (unsigned short)(r >> 16);
}
__device__ __forceinline__ float b2f(unsigned short h) {
  union { unsigned int u; float f; } c; c.u = ((unsigned int)h) << 16;
  return c.f;
}

// ---------------------------------------------------------------------------
// Kernel 1: LSH hash, register-tiled f32 (bitwise-identical dot products to
// the naive chain). Grid (NCHUNK, BB), 256 thr.
// ---------------------------------------------------------------------------
__global__ __launch_bounds__(256) void hash_kernel(const float* __restrict__ qk,
                                                   const float* __restrict__ rot,
                                                   unsigned char* __restrict__ bucket) {
  __shared__ __align__(16) float qsT[64][68];
  __shared__ __align__(16) float rs[2][64][68];
  const int tid = threadIdx.x;
  const int b = blockIdx.y, tile = blockIdx.x;

  {
    const int t = tid >> 2, part = tid & 3;
    const float4* src = (const float4*)(qk + ((size_t)b * SS + (size_t)tile * 64 + t) * DD + part * 16);
    float vals[16];
#pragma unroll
    for (int k = 0; k < 4; ++k) {
      float4 f = src[k];
      vals[k * 4 + 0] = f.x; vals[k * 4 + 1] = f.y; vals[k * 4 + 2] = f.z; vals[k * 4 + 3] = f.w;
    }
#pragma unroll
    for (int k = 0; k < 16; ++k) qsT[part * 16 + k][t] = vals[k];
  }

  const int w = tid >> 6, lane = tid & 63;
  const int tx = lane & 7, ty = lane >> 3;
  const int hbuf = w >> 1;
  const int rowbase = 32 * (w & 1);

  for (int hp = 0; hp < 4; ++hp) {
    __syncthreads();
    {
#pragma unroll
      for (int rep = 0; rep < 32; ++rep) {
        const int flat = rep * 256 + tid;
        const int hb = flat >> 12, f = (flat >> 6) & 63, i = flat & 63;
        rs[hb][f][i] = rot[(size_t)f * (HH * 64) + (2 * hp + hb) * 64 + i];
      }
    }
    __syncthreads();

    const int h = 2 * hp + hbuf;
    float acc[4][8];
#pragma unroll
    for (int r = 0; r < 4; ++r)
#pragma unroll
      for (int c = 0; c < 8; ++c) acc[r][c] = 0.f;

#pragma unroll 8
    for (int f = 0; f < 64; ++f) {
      const float4 qv = *(const float4*)&qsT[f][rowbase + 4 * ty];
      const float4 rv0 = *(const float4*)&rs[hbuf][f][8 * tx];
      const float4 rv1 = *(const float4*)&rs[hbuf][f][8 * tx + 4];
      const float qr[4] = {qv.x, qv.y, qv.z, qv.w};
      const float rc[8] = {rv0.x, rv0.y, rv0.z, rv0.w, rv1.x, rv1.y, rv1.z, rv1.w};
#pragma unroll
      for (int r = 0; r < 4; ++r)
#pragma unroll
        for (int c = 0; c < 8; ++c) acc[r][c] += qr[r] * rc[c];
    }

    unsigned int pack = 0;
#pragma unroll
    for (int r = 0; r < 4; ++r) {
      float bv = -3.4e38f;
      int bi = 0;
#pragma unroll
      for (int c = 0; c < 8; ++c) {
        const int i = 8 * tx + c;
        const float vp = acc[r][c];
        if (vp > bv || (vp == bv && i < bi)) { bv = vp; bi = i; }
        const float vn = -vp;
        if (vn > bv || (vn == bv && (i + 64) < bi)) { bv = vn; bi = i + 64; }
      }
#pragma unroll
      for (int off = 1; off < 8; off <<= 1) {
        const float ov = __shfl_xor(bv, off);
        const int oi = __shfl_xor(bi, off);
        if (ov > bv || (ov == bv && oi < bi)) { bv = ov; bi = oi; }
      }
      pack |= ((unsigned int)bi) << (8 * r);
    }
    if (tx == 0) {
      *(unsigned int*)&bucket[((size_t)(b * HH + h)) * SS + (size_t)tile * 64 + rowbase + 4 * ty] = pack;
    }
  }
}

// ---------------------------------------------------------------------------
// Kernel 2: stable counting sort per (b,h). Ballot-based in-chunk rank.
// ---------------------------------------------------------------------------
__global__ __launch_bounds__(256) void sort_kernel(const unsigned char* __restrict__ bucket,
                                                   int* __restrict__ sticker) {
  __shared__ unsigned char lb[SS];
  __shared__ unsigned int hist[NB * NCHUNK];
  __shared__ unsigned int ssum[256];
  const int tid = threadIdx.x;
  const int bh = blockIdx.x;

  {
    const uint4* src = (const uint4*)(bucket + (size_t)bh * SS);
    uint4* dst = (uint4*)lb;
    dst[tid] = src[tid];
    dst[tid + 256] = src[tid + 256];
  }
#pragma unroll
  for (int k = 0; k < (NB * NCHUNK) / 256; ++k) hist[tid + k * 256] = 0u;
  __syncthreads();

  for (int t = tid; t < SS; t += 256)
    atomicAdd(&hist[(int)lb[t] * NCHUNK + (t >> 6)], 1u);
  __syncthreads();

  unsigned int segsum = 0u;
  const int base = tid * 64;
  for (int e = 0; e < 64; ++e) segsum += hist[base + e];
  ssum[tid] = segsum;
  __syncthreads();
  for (int off = 1; off < 256; off <<= 1) {
    const unsigned int vv = (tid >= off) ? ssum[tid - off] : 0u;
    __syncthreads();
    ssum[tid] += vv;
    __syncthreads();
  }
  unsigned int run = ssum[tid] - segsum;
  for (int e = 0; e < 64; ++e) {
    const unsigned int tv = hist[base + e];
    hist[base + e] = run;
    run += tv;
  }
  __syncthreads();

  const int wid = tid >> 6, lane = tid & 63;
  for (int c = wid; c < NCHUNK; c += 4) {
    const int t = c * 64 + lane;
    const int bk = lb[t];
    unsigned long long mm = ~0ull;
#pragma unroll
    for (int bit = 0; bit < 7; ++bit) {
      const unsigned long long bal = __ballot((bk >> bit) & 1);
      mm &= ((bk >> bit) & 1) ? bal : ~bal;
    }
    const int rank = __popcll(mm & ((1ull << lane) - 1ull));
    const int pos = (int)hist[bk * NCHUNK + c] + rank;
    sticker[(size_t)bh * SS + pos] = t;
  }
}

// ---------------------------------------------------------------------------
// Kernel 3: fused attention: gather rows, scores (MFMA), per-h softmax with
// in-block lse, PV (MFMA). Writes normalized o_h (bf16) and lse_h (f32),
// both scattered by ORIGINAL t. Grid (NB, BB, HH), 256 thr.
// LDS: kb[128][72] u16 region is reused (aliased) for ps[64][136] after the
// score MFMAs complete (barrier-protected).
// ---------------------------------------------------------------------------
__global__ __launch_bounds__(256) void attn_kernel(const float* __restrict__ qk,
                                                   const float* __restrict__ v,
                                                   const int* __restrict__ sticker,
                                                   unsigned short* __restrict__ so,
                                                   float* __restrict__ slogits) {
  __shared__ __align__(16) unsigned short kbps[128 * 72];   // aliased: kb then ps
  __shared__ __align__(16) unsigned short vt[64][136];
  __shared__ int st[128];
  __shared__ float sn_s[64];
  const int tid = threadIdx.x;
  const int bin = blockIdx.x, b = blockIdx.y, h = blockIdx.z;
  const int bh = b * HH + h;
  const int prev = (h * NB + bin + CHUNKS - 1) & (CHUNKS - 1);
  const int ph = prev >> 7, pbin = prev & 127;

  if (tid < 128) {
    const int j = tid;
    const int src = (j < 64) ? (bh * SS + bin * 64 + j)
                             : ((b * HH + ph) * SS + pbin * 64 + (j - 64));
    st[j] = sticker[src];
  }
  __syncthreads();

  {
    const int jrow = tid >> 1, half = tid & 1;
    const int trow = st[jrow];
    {
      const float4* src = (const float4*)(qk + ((size_t)b * SS + trow) * DD + half * 32);
      float vals[32];
      float ssq = 0.f;
#pragma unroll
      for (int k = 0; k < 8; ++k) {
        float4 f = src[k];
        vals[k * 4 + 0] = f.x; vals[k * 4 + 1] = f.y; vals[k * 4 + 2] = f.z; vals[k * 4 + 3] = f.w;
        ssq += f.x * f.x + f.y * f.y + f.z * f.z + f.w * f.w;
      }
      ssq += __shfl_xor(ssq, 1);
      const float r = rsqrtf(ssq + 1e-6f);
      const float sn = (ssq + 1e-6f) * r;  // sqrt(ssq + eps)
      unsigned short* kd = &kbps[jrow * 72 + half * 32];
#pragma unroll
      for (int m = 0; m < 32; ++m) kd[m] = f2b(vals[m] * r);
      if (half == 0 && jrow < 64) sn_s[jrow] = sn;
    }
    {
      const float4* vsrc = (const float4*)(v + ((size_t)b * SS + trow) * DD + half * 32);
#pragma unroll
      for (int k = 0; k < 8; ++k) {
        float4 f = vsrc[k];
        const int d0 = half * 32 + k * 4;
        vt[d0 + 0][jrow] = f2b(f.x);
        vt[d0 + 1][jrow] = f2b(f.y);
        vt[d0 + 2][jrow] = f2b(f.z);
        vt[d0 + 3][jrow] = f2b(f.w);
      }
    }
  }
  __syncthreads();

  const int lane = tid & 63, w = tid >> 6;
  const int r16 = lane & 15, g = lane >> 4;

  // scores: S = (k̂_q · k̂_j) — scaled by snorm_q afterwards
  f32x4 acc[8];
#pragma unroll
  for (int n = 0; n < 8; ++n) acc[n] = (f32x4){0.f, 0.f, 0.f, 0.f};
  bf16x8 af0 = *(const bf16x8*)&kbps[(16 * w + r16) * 72 + g * 8];
  bf16x8 af1 = *(const bf16x8*)&kbps[(16 * w + r16) * 72 + 32 + g * 8];
#pragma unroll
  for (int n = 0; n < 8; ++n) {
    bf16x8 bf0 = *(const bf16x8*)&kbps[(16 * n + r16) * 72 + g * 8];
    bf16x8 bf1 = *(const bf16x8*)&kbps[(16 * n + r16) * 72 + 32 + g * 8];
    acc[n] = __builtin_amdgcn_mfma_f32_16x16x32_bf16(af0, bf0, acc[n], 0, 0, 0);
    acc[n] = __builtin_amdgcn_mfma_f32_16x16x32_bf16(af1, bf1, acc[n], 0, 0, 0);
  }

  int tkj[8];
#pragma unroll
  for (int n = 0; n < 8; ++n) tkj[n] = st[16 * n + r16];

  // per-row (per-h) softmax: mask, lse over 128 keys, p = exp(s - lse)
  float lse4[4];
#pragma unroll
  for (int i = 0; i < 4; ++i) {
    const int q = 16 * w + 4 * g + i;
    const int tq = st[q];
    const float sq = sn_s[q] * 0.125f;
    float mm = -3.4e38f;
#pragma unroll
    for (int n = 0; n < 8; ++n) {
      float s = acc[n][i] * sq;
      s = (tkj[n] > tq) ? -1e38f : ((tkj[n] == tq) ? -50000.f : s);
      acc[n][i] = s;
      mm = fmaxf(mm, s);
    }
    mm = fmaxf(mm, __shfl_xor(mm, 1));
    mm = fmaxf(mm, __shfl_xor(mm, 2));
    mm = fmaxf(mm, __shfl_xor(mm, 4));
    mm = fmaxf(mm, __shfl_xor(mm, 8));
    float sum = 0.f;
#pragma unroll
    for (int n = 0; n < 8; ++n) sum += __expf(acc[n][i] - mm);
    sum += __shfl_xor(sum, 1);
    sum += __shfl_xor(sum, 2);
    sum += __shfl_xor(sum, 4);
    sum += __shfl_xor(sum, 8);
    const float lse = mm + logf(sum);
    lse4[i] = lse;
#pragma unroll
    for (int n = 0; n < 8; ++n) acc[n][i] = __expf(acc[n][i] - lse);
  }

  __syncthreads();  // all kb reads done -> safe to overwrite with ps

#pragma unroll
  for (int i = 0; i < 4; ++i) {
    const int q = 16 * w + 4 * g + i;
#pragma unroll
    for (int n = 0; n < 8; ++n)
      kbps[q * 136 + 16 * n + r16] = f2b(acc[n][i]);
  }
  if (r16 == 0) {
#pragma unroll
    for (int i = 0; i < 4; ++i) {
      const int q = 16 * w + 4 * g + i;
      slogits[(size_t)bh * SS + st[q]] = lse4[i];
    }
  }
  __syncthreads();

  f32x4 o[4];
#pragma unroll
  for (int n = 0; n < 4; ++n) o[n] = (f32x4){0.f, 0.f, 0.f, 0.f};
#pragma unroll
  for (int kk = 0; kk < 4; ++kk) {
    bf16x8 pa = *(const bf16x8*)&kbps[(16 * w + r16) * 136 + kk * 32 + g * 8];
#pragma unroll
    for (int n = 0; n < 4; ++n) {
      bf16x8 vb = *(const bf16x8*)&vt[16 * n + r16][kk * 32 + g * 8];
      o[n] = __builtin_amdgcn_mfma_f32_16x16x32_bf16(pa, vb, o[n], 0, 0, 0);
    }
  }

#pragma unroll
  for (int i = 0; i < 4; ++i) {
    const int q = 16 * w + 4 * g + i;
    unsigned short* dst = so + ((size_t)bh * SS + st[q]) * DD;
#pragma unroll
    for (int n = 0; n < 4; ++n)
      dst[16 * n + r16] = f2b(o[n][i]);
  }
}

// ---------------------------------------------------------------------------
// Kernel 4: combine — out[b,t] = sum_h exp(l_h - LSE) * o_h[b,h,t].
// Fully coalesced (o/logits stored by original t).
// ---------------------------------------------------------------------------
__global__ __launch_bounds__(256) void gather_out_kernel(const unsigned short* __restrict__ so,
                                                         const float* __restrict__ slogits,
                                                         float* __restrict__ out) {
  const int idx = blockIdx.x * 256 + threadIdx.x;  // (b, t, quarter)
  const int quarter = idx & 3;
  const int bt = idx >> 2;
  const int b = bt >> 13, t = bt & (SS - 1);

  float l[HH];
  float m = -3.4e38f;
#pragma unroll
  for (int h = 0; h < HH; ++h) {
    l[h] = slogits[((size_t)(b * HH + h)) * SS + t];
    m = fmaxf(m, l[h]);
  }
  float sum = 0.f;
#pragma unroll
  for (int h = 0; h < HH; ++h) sum += __expf(l[h] - m);
  const float lse = m + logf(sum);

  float acc[16];
#pragma unroll
  for (int k = 0; k < 16; ++k) acc[k] = 0.f;
#pragma unroll
  for (int h = 0; h < HH; ++h) {
    const float wgt = __expf(l[h] - lse);
    const unsigned short* row = so + (((size_t)(b * HH + h)) * SS + t) * DD + quarter * 16;
    unsigned short vals[16];
    *(uint4*)&vals[0] = *(const uint4*)&row[0];
    *(uint4*)&vals[8] = *(const uint4*)&row[8];
#pragma unroll
    for (int k = 0; k < 16; ++k) acc[k] += wgt * b2f(vals[k]);
  }
  float* dst = out + ((size_t)b * SS + t) * DD + quarter * 16;
#pragma unroll
  for (int wq = 0; wq < 4; ++wq) {
    float4 ov;
    ov.x = acc[wq * 4 + 0]; ov.y = acc[wq * 4 + 1];
    ov.z = acc[wq * 4 + 2]; ov.w = acc[wq * 4 + 3];
    ((float4*)dst)[wq] = ov;
  }
}

// ---------------------------------------------------------------------------
extern "C" void kernel_launch(void* const* d_in, const int* in_sizes, int n_in,
                              void* d_out, int out_size, void* d_ws, size_t ws_size,
                              hipStream_t stream) {
  (void)in_sizes; (void)n_in; (void)out_size; (void)ws_size;
  const float* qk = (const float*)d_in[0];
  const float* v = (const float*)d_in[1];
  const float* rot = (const float*)d_in[2];
  float* out = (float*)d_out;

  char* ws = (char*)d_ws;
  int* sticker = (int*)ws;                                        // 2 MB
  float* slogits = (float*)(ws + ((size_t)2 << 20));              // 2 MB
  unsigned char* bucket = (unsigned char*)(ws + ((size_t)4 << 20)); // 512 KB
  unsigned short* so = (unsigned short*)(ws + ((size_t)8 << 20)); // 64 MB

  hash_kernel<<<dim3(NCHUNK, BB), 256, 0, stream>>>(qk, rot, bucket);
  sort_kernel<<<BB * HH, 256, 0, stream>>>(bucket, sticker);
  attn_kernel<<<dim3(NB, BB, HH), 256, 0, stream>>>(qk, v, sticker, so, slogits);
  gather_out_kernel<<<(BB * SS * 4) / 256, 256, 0, stream>>>(so, slogits, out);
}

// Round 5
// 194.832 us; speedup vs baseline: 9.2830x; 1.1539x over previous
//
#include <hip/hip_runtime.h>
#include <cstdint>
#include <cstddef>

#define BB 8
#define SS 8192
#define DD 64
#define HH 8
#define NB 128
#define NCHUNK 128   /* S / 64 */
#define CHUNKS 1024  /* H * NB */

typedef __attribute__((ext_vector_type(8))) short bf16x8;
typedef __attribute__((ext_vector_type(4))) float f32x4;

__device__ __forceinline__ unsigned short f2b(float x) {
  union { float f; unsigned int u; } c; c.f = x;
  unsigned int r = c.u + 0x7fffu + ((c.u >> 16) & 1u);
  return (unsigned short)(r >> 16);
}
__device__ __forceinline__ float b2f(unsigned short h) {
  union { unsigned int u; float f; } c; c.u = ((unsigned int)h) << 16;
  return c.f;
}

// ---------------------------------------------------------------------------
// Kernel 0: prep — qhat = normalize(qk) in bf16, snorm = sqrt(ssq+eps) f32,
// vb = v in bf16. Fully coalesced. 8 lanes per row.
// ---------------------------------------------------------------------------
__global__ __launch_bounds__(256) void prep_kernel(const float* __restrict__ qk,
                                                   const float* __restrict__ v,
                                                   unsigned short* __restrict__ qhat,
                                                   unsigned short* __restrict__ vb,
                                                   float* __restrict__ snorm) {
  const int idx = blockIdx.x * 256 + threadIdx.x;
  const int row = idx >> 3, seg = idx & 7;
  const size_t base = (size_t)row * DD + seg * 8;

  float4 a0 = ((const float4*)(qk + base))[0];
  float4 a1 = ((const float4*)(qk + base))[1];
  float vals[8] = {a0.x, a0.y, a0.z, a0.w, a1.x, a1.y, a1.z, a1.w};
  float ssq = 0.f;
#pragma unroll
  for (int k = 0; k < 8; ++k) ssq += vals[k] * vals[k];
  ssq += __shfl_xor(ssq, 1);
  ssq += __shfl_xor(ssq, 2);
  ssq += __shfl_xor(ssq, 4);
  const float r = rsqrtf(ssq + 1e-6f);
  const float sn = (ssq + 1e-6f) * r;  // sqrt(ssq + eps)
  uint4 qo;
  unsigned int* qp = (unsigned int*)&qo;
#pragma unroll
  for (int k = 0; k < 4; ++k)
    qp[k] = (unsigned int)f2b(vals[2 * k] * r) | ((unsigned int)f2b(vals[2 * k + 1] * r) << 16);
  *(uint4*)(qhat + base) = qo;
  if (seg == 0) snorm[row] = sn;

  float4 v0 = ((const float4*)(v + base))[0];
  float4 v1 = ((const float4*)(v + base))[1];
  float vv[8] = {v0.x, v0.y, v0.z, v0.w, v1.x, v1.y, v1.z, v1.w};
  uint4 vo;
  unsigned int* vp = (unsigned int*)&vo;
#pragma unroll
  for (int k = 0; k < 4; ++k)
    vp[k] = (unsigned int)f2b(vv[2 * k]) | ((unsigned int)f2b(vv[2 * k + 1]) << 16);
  *(uint4*)(vb + base) = vo;
}

// ---------------------------------------------------------------------------
// Kernel 1: LSH hash, register-tiled f32 (bitwise-identical dot products to
// the naive chain). Grid (NCHUNK, BB), 256 thr.
// ---------------------------------------------------------------------------
__global__ __launch_bounds__(256) void hash_kernel(const float* __restrict__ qk,
                                                   const float* __restrict__ rot,
                                                   unsigned char* __restrict__ bucket) {
  __shared__ __align__(16) float qsT[64][68];
  __shared__ __align__(16) float rs[2][64][68];
  const int tid = threadIdx.x;
  const int b = blockIdx.y, tile = blockIdx.x;

  {
    const int t = tid >> 2, part = tid & 3;
    const float4* src = (const float4*)(qk + ((size_t)b * SS + (size_t)tile * 64 + t) * DD + part * 16);
    float vals[16];
#pragma unroll
    for (int k = 0; k < 4; ++k) {
      float4 f = src[k];
      vals[k * 4 + 0] = f.x; vals[k * 4 + 1] = f.y; vals[k * 4 + 2] = f.z; vals[k * 4 + 3] = f.w;
    }
#pragma unroll
    for (int k = 0; k < 16; ++k) qsT[part * 16 + k][t] = vals[k];
  }

  const int w = tid >> 6, lane = tid & 63;
  const int tx = lane & 7, ty = lane >> 3;
  const int hbuf = w >> 1;
  const int rowbase = 32 * (w & 1);

  for (int hp = 0; hp < 4; ++hp) {
    __syncthreads();
    {
#pragma unroll
      for (int rep = 0; rep < 32; ++rep) {
        const int flat = rep * 256 + tid;
        const int hb = flat >> 12, f = (flat >> 6) & 63, i = flat & 63;
        rs[hb][f][i] = rot[(size_t)f * (HH * 64) + (2 * hp + hb) * 64 + i];
      }
    }
    __syncthreads();

    const int h = 2 * hp + hbuf;
    float acc[4][8];
#pragma unroll
    for (int r = 0; r < 4; ++r)
#pragma unroll
      for (int c = 0; c < 8; ++c) acc[r][c] = 0.f;

#pragma unroll 8
    for (int f = 0; f < 64; ++f) {
      const float4 qv = *(const float4*)&qsT[f][rowbase + 4 * ty];
      const float4 rv0 = *(const float4*)&rs[hbuf][f][8 * tx];
      const float4 rv1 = *(const float4*)&rs[hbuf][f][8 * tx + 4];
      const float qr[4] = {qv.x, qv.y, qv.z, qv.w};
      const float rc[8] = {rv0.x, rv0.y, rv0.z, rv0.w, rv1.x, rv1.y, rv1.z, rv1.w};
#pragma unroll
      for (int r = 0; r < 4; ++r)
#pragma unroll
        for (int c = 0; c < 8; ++c) acc[r][c] += qr[r] * rc[c];
    }

    unsigned int pack = 0;
#pragma unroll
    for (int r = 0; r < 4; ++r) {
      float bv = -3.4e38f;
      int bi = 0;
#pragma unroll
      for (int c = 0; c < 8; ++c) {
        const int i = 8 * tx + c;
        const float vp = acc[r][c];
        if (vp > bv || (vp == bv && i < bi)) { bv = vp; bi = i; }
        const float vn = -vp;
        if (vn > bv || (vn == bv && (i + 64) < bi)) { bv = vn; bi = i + 64; }
      }
#pragma unroll
      for (int off = 1; off < 8; off <<= 1) {
        const float ov = __shfl_xor(bv, off);
        const int oi = __shfl_xor(bi, off);
        if (ov > bv || (ov == bv && oi < bi)) { bv = ov; bi = oi; }
      }
      pack |= ((unsigned int)bi) << (8 * r);
    }
    if (tx == 0) {
      *(unsigned int*)&bucket[((size_t)(b * HH + h)) * SS + (size_t)tile * 64 + rowbase + 4 * ty] = pack;
    }
  }
}

// ---------------------------------------------------------------------------
// Kernel 2: stable counting sort per (b,h), 1024 threads.
// ---------------------------------------------------------------------------
__global__ __launch_bounds__(1024) void sort_kernel(const unsigned char* __restrict__ bucket,
                                                    int* __restrict__ sticker) {
  __shared__ unsigned char lb[SS];
  __shared__ unsigned int hist[NB * NCHUNK];
  __shared__ unsigned int ssum[1024];
  const int tid = threadIdx.x;
  const int bh = blockIdx.x;

  if (tid < 512)
    ((uint4*)lb)[tid] = ((const uint4*)(bucket + (size_t)bh * SS))[tid];
#pragma unroll
  for (int k = 0; k < (NB * NCHUNK) / 1024; ++k) hist[tid + k * 1024] = 0u;
  __syncthreads();

#pragma unroll
  for (int rep = 0; rep < SS / 1024; ++rep) {
    const int t = rep * 1024 + tid;
    atomicAdd(&hist[(int)lb[t] * NCHUNK + (t >> 6)], 1u);
  }
  __syncthreads();

  unsigned int segsum = 0u;
  const int base = tid * 16;
#pragma unroll
  for (int e = 0; e < 16; ++e) segsum += hist[base + e];
  ssum[tid] = segsum;
  __syncthreads();
  for (int off = 1; off < 1024; off <<= 1) {
    const unsigned int vv = (tid >= off) ? ssum[tid - off] : 0u;
    __syncthreads();
    ssum[tid] += vv;
    __syncthreads();
  }
  unsigned int run = ssum[tid] - segsum;
#pragma unroll
  for (int e = 0; e < 16; ++e) {
    const unsigned int tv = hist[base + e];
    hist[base + e] = run;
    run += tv;
  }
  __syncthreads();

  const int wid = tid >> 6, lane = tid & 63;
#pragma unroll
  for (int rep = 0; rep < NCHUNK / 16; ++rep) {
    const int c = rep * 16 + wid;
    const int t = c * 64 + lane;
    const int bk = lb[t];
    unsigned long long mm = ~0ull;
#pragma unroll
    for (int bit = 0; bit < 7; ++bit) {
      const unsigned long long bal = __ballot((bk >> bit) & 1);
      mm &= ((bk >> bit) & 1) ? bal : ~bal;
    }
    const int rank = __popcll(mm & ((1ull << lane) - 1ull));
    const int pos = (int)hist[bk * NCHUNK + c] + rank;
    sticker[(size_t)bh * SS + pos] = t;
  }
}

// ---------------------------------------------------------------------------
// Kernel 3: fused attention from precomputed bf16 qhat/vb + f32 snorm.
// Grid (NB, 4, HH) per b-half. Writes normalized o_h (bf16, layout b,t,h,d)
// and lse_h (f32, layout b,t,h), scattered by original t.
// ---------------------------------------------------------------------------
__global__ __launch_bounds__(256) void attn_kernel(const unsigned short* __restrict__ qhat,
                                                   const unsigned short* __restrict__ vb,
                                                   const float* __restrict__ snorm,
                                                   const int* __restrict__ sticker,
                                                   unsigned short* __restrict__ so,
                                                   float* __restrict__ slogits,
                                                   const int b_base) {
  __shared__ __align__(16) unsigned short kbps[128 * 72];   // aliased: kb -> ps -> ob
  __shared__ __align__(16) unsigned short vt[64][136];
  __shared__ int st[128];
  __shared__ float sn_s[64];
  const int tid = threadIdx.x;
  const int bin = blockIdx.x, bl = blockIdx.y, h = blockIdx.z;
  const int b = b_base + bl;
  const int bh = b * HH + h;
  const int prev = (h * NB + bin + CHUNKS - 1) & (CHUNKS - 1);
  const int ph = prev >> 7, pbin = prev & 127;

  if (tid < 128) {
    const int j = tid;
    const int src = (j < 64) ? (bh * SS + bin * 64 + j)
                             : ((b * HH + ph) * SS + pbin * 64 + (j - 64));
    st[j] = sticker[src];
  }
  __syncthreads();

  {
    const int row = tid >> 1, half = tid & 1;
    const int trow = st[row];
    // k̂ rows (bf16): 4x uint4 -> 4x b128 LDS
    {
      const uint4* qsrc = (const uint4*)(qhat + ((size_t)b * SS + trow) * DD) + half * 4;
      uint4 q0 = qsrc[0], q1 = qsrc[1], q2 = qsrc[2], q3 = qsrc[3];
      unsigned short* kd = &kbps[row * 72 + half * 32];
      *(uint4*)&kd[0] = q0;
      *(uint4*)&kd[8] = q1;
      *(uint4*)&kd[16] = q2;
      *(uint4*)&kd[24] = q3;
    }
    // v rows (bf16) -> transposed vt
    {
      const uint4* vsrc = (const uint4*)(vb + ((size_t)b * SS + trow) * DD) + half * 4;
      uint4 w0 = vsrc[0], w1 = vsrc[1], w2 = vsrc[2], w3 = vsrc[3];
      unsigned int uu[16] = {w0.x, w0.y, w0.z, w0.w, w1.x, w1.y, w1.z, w1.w,
                             w2.x, w2.y, w2.z, w2.w, w3.x, w3.y, w3.z, w3.w};
#pragma unroll
      for (int m = 0; m < 16; ++m) {
        vt[half * 32 + 2 * m][row] = (unsigned short)(uu[m] & 0xffffu);
        vt[half * 32 + 2 * m + 1][row] = (unsigned short)(uu[m] >> 16);
      }
    }
  }
  if (tid < 64) sn_s[tid] = snorm[(size_t)b * SS + st[tid]];
  __syncthreads();

  const int lane = tid & 63, w = tid >> 6;
  const int r16 = lane & 15, g = lane >> 4;

  f32x4 acc[8];
#pragma unroll
  for (int n = 0; n < 8; ++n) acc[n] = (f32x4){0.f, 0.f, 0.f, 0.f};
  bf16x8 af0 = *(const bf16x8*)&kbps[(16 * w + r16) * 72 + g * 8];
  bf16x8 af1 = *(const bf16x8*)&kbps[(16 * w + r16) * 72 + 32 + g * 8];
#pragma unroll
  for (int n = 0; n < 8; ++n) {
    bf16x8 bf0 = *(const bf16x8*)&kbps[(16 * n + r16) * 72 + g * 8];
    bf16x8 bf1 = *(const bf16x8*)&kbps[(16 * n + r16) * 72 + 32 + g * 8];
    acc[n] = __builtin_amdgcn_mfma_f32_16x16x32_bf16(af0, bf0, acc[n], 0, 0, 0);
    acc[n] = __builtin_amdgcn_mfma_f32_16x16x32_bf16(af1, bf1, acc[n], 0, 0, 0);
  }

  int tkj[8];
#pragma unroll
  for (int n = 0; n < 8; ++n) tkj[n] = st[16 * n + r16];

  float lse4[4];
#pragma unroll
  for (int i = 0; i < 4; ++i) {
    const int q = 16 * w + 4 * g + i;
    const int tq = st[q];
    const float sq = sn_s[q] * 0.125f;
    float mm = -3.4e38f;
#pragma unroll
    for (int n = 0; n < 8; ++n) {
      float s = acc[n][i] * sq;
      s = (tkj[n] > tq) ? -1e38f : ((tkj[n] == tq) ? -50000.f : s);
      acc[n][i] = s;
      mm = fmaxf(mm, s);
    }
    mm = fmaxf(mm, __shfl_xor(mm, 1));
    mm = fmaxf(mm, __shfl_xor(mm, 2));
    mm = fmaxf(mm, __shfl_xor(mm, 4));
    mm = fmaxf(mm, __shfl_xor(mm, 8));
    float sum = 0.f;
#pragma unroll
    for (int n = 0; n < 8; ++n) sum += __expf(acc[n][i] - mm);
    sum += __shfl_xor(sum, 1);
    sum += __shfl_xor(sum, 2);
    sum += __shfl_xor(sum, 4);
    sum += __shfl_xor(sum, 8);
    const float lse = mm + logf(sum);
    lse4[i] = lse;
#pragma unroll
    for (int n = 0; n < 8; ++n) acc[n][i] = __expf(acc[n][i] - lse);
  }

  __syncthreads();  // kb reads done -> overwrite with ps

#pragma unroll
  for (int i = 0; i < 4; ++i) {
    const int q = 16 * w + 4 * g + i;
#pragma unroll
    for (int n = 0; n < 8; ++n)
      kbps[q * 136 + 16 * n + r16] = f2b(acc[n][i]);
  }
  if (r16 == 0) {
#pragma unroll
    for (int i = 0; i < 4; ++i) {
      const int q = 16 * w + 4 * g + i;
      slogits[((size_t)b * SS + st[q]) * HH + h] = lse4[i];
    }
  }
  __syncthreads();

  f32x4 o[4];
#pragma unroll
  for (int n = 0; n < 4; ++n) o[n] = (f32x4){0.f, 0.f, 0.f, 0.f};
#pragma unroll
  for (int kk = 0; kk < 4; ++kk) {
    bf16x8 pa = *(const bf16x8*)&kbps[(16 * w + r16) * 136 + kk * 32 + g * 8];
#pragma unroll
    for (int n = 0; n < 4; ++n) {
      bf16x8 vbf = *(const bf16x8*)&vt[16 * n + r16][kk * 32 + g * 8];
      o[n] = __builtin_amdgcn_mfma_f32_16x16x32_bf16(pa, vbf, o[n], 0, 0, 0);
    }
  }

  __syncthreads();  // ps reads done -> overwrite with ob
#pragma unroll
  for (int i = 0; i < 4; ++i) {
    const int q = 16 * w + 4 * g + i;
#pragma unroll
    for (int n = 0; n < 4; ++n)
      kbps[q * 72 + 16 * n + r16] = f2b(o[n][i]);
  }
  __syncthreads();

  {
    const int row = tid >> 2, q4 = tid & 3;
    uint4 x0 = *(const uint4*)&kbps[row * 72 + q4 * 16];
    uint4 x1 = *(const uint4*)&kbps[row * 72 + q4 * 16 + 8];
    unsigned short* dst = so + (((size_t)bl * SS + st[row]) * HH + h) * DD + q4 * 16;
    *(uint4*)&dst[0] = x0;
    *(uint4*)&dst[8] = x1;
  }
}

// ---------------------------------------------------------------------------
// Kernel 4: combine — out[b,t] = sum_h exp(l_h - LSE) * o_h[b,t,h].
// so layout (local b, t, h, d): contiguous per token.
// ---------------------------------------------------------------------------
__global__ __launch_bounds__(256) void gather_out_kernel(const unsigned short* __restrict__ so,
                                                         const float* __restrict__ slogits,
                                                         float* __restrict__ out,
                                                         const int b_base) {
  const int idx = blockIdx.x * 256 + threadIdx.x;  // (local bt, seg)
  const int seg = idx & 7;
  const int btl = idx >> 3;  // local row in [0, 4*SS)

  const float* lrow = slogits + ((size_t)b_base * SS + btl) * HH;
  float4 l0 = ((const float4*)lrow)[0];
  float4 l1 = ((const float4*)lrow)[1];
  float l[8] = {l0.x, l0.y, l0.z, l0.w, l1.x, l1.y, l1.z, l1.w};
  float m = -3.4e38f;
#pragma unroll
  for (int h = 0; h < HH; ++h) m = fmaxf(m, l[h]);
  float sum = 0.f;
#pragma unroll
  for (int h = 0; h < HH; ++h) sum += __expf(l[h] - m);
  const float lse = m + logf(sum);

  float acc[8];
#pragma unroll
  for (int k = 0; k < 8; ++k) acc[k] = 0.f;
#pragma unroll
  for (int h = 0; h < HH; ++h) {
    const float wgt = __expf(l[h] - lse);
    uint4 u = *(const uint4*)(so + ((size_t)btl * HH + h) * DD + seg * 8);
    const unsigned int uu[4] = {u.x, u.y, u.z, u.w};
#pragma unroll
    for (int k = 0; k < 4; ++k) {
      acc[2 * k] += wgt * b2f((unsigned short)(uu[k] & 0xffffu));
      acc[2 * k + 1] += wgt * b2f((unsigned short)(uu[k] >> 16));
    }
  }
  float* dst = out + ((size_t)b_base * SS + btl) * DD + seg * 8;
  float4 o0, o1;
  o0.x = acc[0]; o0.y = acc[1]; o0.z = acc[2]; o0.w = acc[3];
  o1.x = acc[4]; o1.y = acc[5]; o1.z = acc[6]; o1.w = acc[7];
  ((float4*)dst)[0] = o0;
  ((float4*)dst)[1] = o1;
}

// ---------------------------------------------------------------------------
extern "C" void kernel_launch(void* const* d_in, const int* in_sizes, int n_in,
                              void* d_out, int out_size, void* d_ws, size_t ws_size,
                              hipStream_t stream) {
  (void)in_sizes; (void)n_in; (void)out_size; (void)ws_size;
  const float* qk = (const float*)d_in[0];
  const float* v = (const float*)d_in[1];
  const float* rot = (const float*)d_in[2];
  float* out = (float*)d_out;

  char* ws = (char*)d_ws;
  int* sticker = (int*)ws;                                          // @0,   2 MB
  float* slogits = (float*)(ws + ((size_t)2 << 20));                // @2,   2 MB (b,t,h)
  float* snorm = (float*)(ws + ((size_t)4 << 20));                  // @4,   256 KB
  unsigned char* bucket = (unsigned char*)(ws + ((size_t)4 << 20) + ((size_t)256 << 10));  // 512 KB
  unsigned short* qhat = (unsigned short*)(ws + ((size_t)5 << 20)); // @5,   8 MB
  unsigned short* vb = (unsigned short*)(ws + ((size_t)13 << 20));  // @13,  8 MB
  unsigned short* so = (unsigned short*)(ws + ((size_t)21 << 20));  // @21, 32 MB (half-batch)

  prep_kernel<<<(BB * SS * 8) / 256, 256, 0, stream>>>(qk, v, qhat, vb, snorm);
  hash_kernel<<<dim3(NCHUNK, BB), 256, 0, stream>>>(qk, rot, bucket);
  sort_kernel<<<BB * HH, 1024, 0, stream>>>(bucket, sticker);

  for (int half = 0; half < 2; ++half) {
    const int b_base = half * (BB / 2);
    attn_kernel<<<dim3(NB, BB / 2, HH), 256, 0, stream>>>(qhat, vb, snorm, sticker, so, slogits, b_base);
    gather_out_kernel<<<(BB / 2 * SS * 8) / 256, 256, 0, stream>>>(so, slogits, out, b_base);
  }
}

// Round 6
// 191.356 us; speedup vs baseline: 9.4516x; 1.0182x over previous
//
#include <hip/hip_runtime.h>
#include <cstdint>
#include <cstddef>

#define BB 8
#define SS 8192
#define DD 64
#define HH 8
#define NB 128
#define NCHUNK 128   /* S / 64 */
#define CHUNKS 1024  /* H * NB */

typedef __attribute__((ext_vector_type(8))) short bf16x8;
typedef __attribute__((ext_vector_type(4))) float f32x4;

__device__ __forceinline__ unsigned short f2b(float x) {
  union { float f; unsigned int u; } c; c.f = x;
  unsigned int r = c.u + 0x7fffu + ((c.u >> 16) & 1u);
  return (unsigned short)(r >> 16);
}
__device__ __forceinline__ float b2f(unsigned short h) {
  union { unsigned int u; float f; } c; c.u = ((unsigned int)h) << 16;
  return c.f;
}

// ---------------------------------------------------------------------------
// Kernel 0: prep — qhat = normalize(qk) in bf16, snorm = sqrt(ssq+eps) f32,
// vb = v in bf16. Fully coalesced. 8 lanes per row.
// ---------------------------------------------------------------------------
__global__ __launch_bounds__(256) void prep_kernel(const float* __restrict__ qk,
                                                   const float* __restrict__ v,
                                                   unsigned short* __restrict__ qhat,
                                                   unsigned short* __restrict__ vb,
                                                   float* __restrict__ snorm) {
  const int idx = blockIdx.x * 256 + threadIdx.x;
  const int row = idx >> 3, seg = idx & 7;
  const size_t base = (size_t)row * DD + seg * 8;

  float4 a0 = ((const float4*)(qk + base))[0];
  float4 a1 = ((const float4*)(qk + base))[1];
  float vals[8] = {a0.x, a0.y, a0.z, a0.w, a1.x, a1.y, a1.z, a1.w};
  float ssq = 0.f;
#pragma unroll
  for (int k = 0; k < 8; ++k) ssq += vals[k] * vals[k];
  ssq += __shfl_xor(ssq, 1);
  ssq += __shfl_xor(ssq, 2);
  ssq += __shfl_xor(ssq, 4);
  const float r = rsqrtf(ssq + 1e-6f);
  const float sn = (ssq + 1e-6f) * r;  // sqrt(ssq + eps)
  uint4 qo;
  unsigned int* qp = (unsigned int*)&qo;
#pragma unroll
  for (int k = 0; k < 4; ++k)
    qp[k] = (unsigned int)f2b(vals[2 * k] * r) | ((unsigned int)f2b(vals[2 * k + 1] * r) << 16);
  *(uint4*)(qhat + base) = qo;
  if (seg == 0) snorm[row] = sn;

  float4 v0 = ((const float4*)(v + base))[0];
  float4 v1 = ((const float4*)(v + base))[1];
  float vv[8] = {v0.x, v0.y, v0.z, v0.w, v1.x, v1.y, v1.z, v1.w};
  uint4 vo;
  unsigned int* vp = (unsigned int*)&vo;
#pragma unroll
  for (int k = 0; k < 4; ++k)
    vp[k] = (unsigned int)f2b(vv[2 * k]) | ((unsigned int)f2b(vv[2 * k + 1]) << 16);
  *(uint4*)(vb + base) = vo;
}

// ---------------------------------------------------------------------------
// Kernel 1: LSH hash, register-tiled f32, single-buffered rs (one h per
// phase) for 4 blocks/CU occupancy. Dot-product chains bitwise-identical to
// the passing version (serial f=0..63). Grid (NCHUNK, BB), 256 thr.
// Thread tile: 4 rows x 4 cols. Per f: 2x ds_read_b128 + 16 v_fma.
// ---------------------------------------------------------------------------
__global__ __launch_bounds__(256) void hash_kernel(const float* __restrict__ qk,
                                                   const float* __restrict__ rot,
                                                   unsigned char* __restrict__ bucket) {
  __shared__ __align__(16) float qsT[64][68];
  __shared__ __align__(16) float rs[64][68];
  const int tid = threadIdx.x;
  const int b = blockIdx.y, tile = blockIdx.x;

  // stage qsT (transposed): thread loads 16 consecutive f of row t
  {
    const int t = tid >> 2, part = tid & 3;
    const float4* src = (const float4*)(qk + ((size_t)b * SS + (size_t)tile * 64 + t) * DD + part * 16);
    float vals[16];
#pragma unroll
    for (int k = 0; k < 4; ++k) {
      float4 f = src[k];
      vals[k * 4 + 0] = f.x; vals[k * 4 + 1] = f.y; vals[k * 4 + 2] = f.z; vals[k * 4 + 3] = f.w;
    }
#pragma unroll
    for (int k = 0; k < 16; ++k) qsT[part * 16 + k][t] = vals[k];
  }

  const int w = tid >> 6, lane = tid & 63;
  const int c4 = lane & 15, r4 = lane >> 4;
  const int row0 = 16 * w + 4 * r4;   // rows row0..row0+3
  const int col0 = 4 * c4;            // cols col0..col0+3

  for (int h = 0; h < HH; ++h) {
    __syncthreads();  // previous phase's rs readers done (qsT ready on iter 0)
    // stage rs for this h: each wave reads one contiguous 256B row per rep
#pragma unroll
    for (int rep = 0; rep < 16; ++rep) {
      const int idx = rep * 256 + tid;
      const int f = idx >> 6, i = idx & 63;
      rs[f][i] = rot[(size_t)f * (HH * 64) + h * 64 + i];
    }
    __syncthreads();

    float acc[4][4];
#pragma unroll
    for (int r = 0; r < 4; ++r)
#pragma unroll
      for (int c = 0; c < 4; ++c) acc[r][c] = 0.f;

#pragma unroll 8
    for (int f = 0; f < 64; ++f) {
      const float4 qv = *(const float4*)&qsT[f][row0];
      const float4 rv = *(const float4*)&rs[f][col0];
      const float qr[4] = {qv.x, qv.y, qv.z, qv.w};
      const float rc[4] = {rv.x, rv.y, rv.z, rv.w};
#pragma unroll
      for (int r = 0; r < 4; ++r)
#pragma unroll
        for (int c = 0; c < 4; ++c) acc[r][c] += qr[r] * rc[c];
    }

    // per-row argmax over [rot, -rot]; reduce over the 16 col-lanes.
    // Tie rule: greater value, then lower index (pos indices < neg indices).
    unsigned int pack = 0;
#pragma unroll
    for (int r = 0; r < 4; ++r) {
      float bv = -3.4e38f;
      int bi = 0;
#pragma unroll
      for (int c = 0; c < 4; ++c) {
        const int i = col0 + c;
        const float vp = acc[r][c];
        if (vp > bv || (vp == bv && i < bi)) { bv = vp; bi = i; }
        const float vn = -vp;
        if (vn > bv || (vn == bv && (i + 64) < bi)) { bv = vn; bi = i + 64; }
      }
#pragma unroll
      for (int off = 1; off < 16; off <<= 1) {
        const float ov = __shfl_xor(bv, off);
        const int oi = __shfl_xor(bi, off);
        if (ov > bv || (ov == bv && oi < bi)) { bv = ov; bi = oi; }
      }
      pack |= ((unsigned int)bi) << (8 * r);
    }
    if (c4 == 0) {
      *(unsigned int*)&bucket[((size_t)(b * HH + h)) * SS + (size_t)tile * 64 + row0] = pack;
    }
  }
}

// ---------------------------------------------------------------------------
// Kernel 2: stable counting sort per (b,h), 1024 threads.
// ---------------------------------------------------------------------------
__global__ __launch_bounds__(1024) void sort_kernel(const unsigned char* __restrict__ bucket,
                                                    int* __restrict__ sticker) {
  __shared__ unsigned char lb[SS];
  __shared__ unsigned int hist[NB * NCHUNK];
  __shared__ unsigned int ssum[1024];
  const int tid = threadIdx.x;
  const int bh = blockIdx.x;

  if (tid < 512)
    ((uint4*)lb)[tid] = ((const uint4*)(bucket + (size_t)bh * SS))[tid];
#pragma unroll
  for (int k = 0; k < (NB * NCHUNK) / 1024; ++k) hist[tid + k * 1024] = 0u;
  __syncthreads();

#pragma unroll
  for (int rep = 0; rep < SS / 1024; ++rep) {
    const int t = rep * 1024 + tid;
    atomicAdd(&hist[(int)lb[t] * NCHUNK + (t >> 6)], 1u);
  }
  __syncthreads();

  unsigned int segsum = 0u;
  const int base = tid * 16;
#pragma unroll
  for (int e = 0; e < 16; ++e) segsum += hist[base + e];
  ssum[tid] = segsum;
  __syncthreads();
  for (int off = 1; off < 1024; off <<= 1) {
    const unsigned int vv = (tid >= off) ? ssum[tid - off] : 0u;
    __syncthreads();
    ssum[tid] += vv;
    __syncthreads();
  }
  unsigned int run = ssum[tid] - segsum;
#pragma unroll
  for (int e = 0; e < 16; ++e) {
    const unsigned int tv = hist[base + e];
    hist[base + e] = run;
    run += tv;
  }
  __syncthreads();

  const int wid = tid >> 6, lane = tid & 63;
#pragma unroll
  for (int rep = 0; rep < NCHUNK / 16; ++rep) {
    const int c = rep * 16 + wid;
    const int t = c * 64 + lane;
    const int bk = lb[t];
    unsigned long long mm = ~0ull;
#pragma unroll
    for (int bit = 0; bit < 7; ++bit) {
      const unsigned long long bal = __ballot((bk >> bit) & 1);
      mm &= ((bk >> bit) & 1) ? bal : ~bal;
    }
    const int rank = __popcll(mm & ((1ull << lane) - 1ull));
    const int pos = (int)hist[bk * NCHUNK + c] + rank;
    sticker[(size_t)bh * SS + pos] = t;
  }
}

// ---------------------------------------------------------------------------
// Kernel 3: fused attention from precomputed bf16 qhat/vb + f32 snorm.
// Grid (NB, 4, HH) per b-half. Writes normalized o_h (bf16, layout b,t,h,d)
// and lse_h (f32, layout b,t,h), scattered by original t.
// ---------------------------------------------------------------------------
__global__ __launch_bounds__(256) void attn_kernel(const unsigned short* __restrict__ qhat,
                                                   const unsigned short* __restrict__ vb,
                                                   const float* __restrict__ snorm,
                                                   const int* __restrict__ sticker,
                                                   unsigned short* __restrict__ so,
                                                   float* __restrict__ slogits,
                                                   const int b_base) {
  __shared__ __align__(16) unsigned short kbps[128 * 72];   // aliased: kb -> ps -> ob
  __shared__ __align__(16) unsigned short vt[64][136];
  __shared__ int st[128];
  __shared__ float sn_s[64];
  const int tid = threadIdx.x;
  const int bin = blockIdx.x, bl = blockIdx.y, h = blockIdx.z;
  const int b = b_base + bl;
  const int bh = b * HH + h;
  const int prev = (h * NB + bin + CHUNKS - 1) & (CHUNKS - 1);
  const int ph = prev >> 7, pbin = prev & 127;

  if (tid < 128) {
    const int j = tid;
    const int src = (j < 64) ? (bh * SS + bin * 64 + j)
                             : ((b * HH + ph) * SS + pbin * 64 + (j - 64));
    st[j] = sticker[src];
  }
  __syncthreads();

  {
    const int row = tid >> 1, half = tid & 1;
    const int trow = st[row];
    {
      const uint4* qsrc = (const uint4*)(qhat + ((size_t)b * SS + trow) * DD) + half * 4;
      uint4 q0 = qsrc[0], q1 = qsrc[1], q2 = qsrc[2], q3 = qsrc[3];
      unsigned short* kd = &kbps[row * 72 + half * 32];
      *(uint4*)&kd[0] = q0;
      *(uint4*)&kd[8] = q1;
      *(uint4*)&kd[16] = q2;
      *(uint4*)&kd[24] = q3;
    }
    {
      const uint4* vsrc = (const uint4*)(vb + ((size_t)b * SS + trow) * DD) + half * 4;
      uint4 w0 = vsrc[0], w1 = vsrc[1], w2 = vsrc[2], w3 = vsrc[3];
      unsigned int uu[16] = {w0.x, w0.y, w0.z, w0.w, w1.x, w1.y, w1.z, w1.w,
                             w2.x, w2.y, w2.z, w2.w, w3.x, w3.y, w3.z, w3.w};
#pragma unroll
      for (int m = 0; m < 16; ++m) {
        vt[half * 32 + 2 * m][row] = (unsigned short)(uu[m] & 0xffffu);
        vt[half * 32 + 2 * m + 1][row] = (unsigned short)(uu[m] >> 16);
      }
    }
  }
  if (tid < 64) sn_s[tid] = snorm[(size_t)b * SS + st[tid]];
  __syncthreads();

  const int lane = tid & 63, w = tid >> 6;
  const int r16 = lane & 15, g = lane >> 4;

  f32x4 acc[8];
#pragma unroll
  for (int n = 0; n < 8; ++n) acc[n] = (f32x4){0.f, 0.f, 0.f, 0.f};
  bf16x8 af0 = *(const bf16x8*)&kbps[(16 * w + r16) * 72 + g * 8];
  bf16x8 af1 = *(const bf16x8*)&kbps[(16 * w + r16) * 72 + 32 + g * 8];
#pragma unroll
  for (int n = 0; n < 8; ++n) {
    bf16x8 bf0 = *(const bf16x8*)&kbps[(16 * n + r16) * 72 + g * 8];
    bf16x8 bf1 = *(const bf16x8*)&kbps[(16 * n + r16) * 72 + 32 + g * 8];
    acc[n] = __builtin_amdgcn_mfma_f32_16x16x32_bf16(af0, bf0, acc[n], 0, 0, 0);
    acc[n] = __builtin_amdgcn_mfma_f32_16x16x32_bf16(af1, bf1, acc[n], 0, 0, 0);
  }

  int tkj[8];
#pragma unroll
  for (int n = 0; n < 8; ++n) tkj[n] = st[16 * n + r16];

  float lse4[4];
#pragma unroll
  for (int i = 0; i < 4; ++i) {
    const int q = 16 * w + 4 * g + i;
    const int tq = st[q];
    const float sq = sn_s[q] * 0.125f;
    float mm = -3.4e38f;
#pragma unroll
    for (int n = 0; n < 8; ++n) {
      float s = acc[n][i] * sq;
      s = (tkj[n] > tq) ? -1e38f : ((tkj[n] == tq) ? -50000.f : s);
      acc[n][i] = s;
      mm = fmaxf(mm, s);
    }
    mm = fmaxf(mm, __shfl_xor(mm, 1));
    mm = fmaxf(mm, __shfl_xor(mm, 2));
    mm = fmaxf(mm, __shfl_xor(mm, 4));
    mm = fmaxf(mm, __shfl_xor(mm, 8));
    float sum = 0.f;
#pragma unroll
    for (int n = 0; n < 8; ++n) sum += __expf(acc[n][i] - mm);
    sum += __shfl_xor(sum, 1);
    sum += __shfl_xor(sum, 2);
    sum += __shfl_xor(sum, 4);
    sum += __shfl_xor(sum, 8);
    const float lse = mm + logf(sum);
    lse4[i] = lse;
#pragma unroll
    for (int n = 0; n < 8; ++n) acc[n][i] = __expf(acc[n][i] - lse);
  }

  __syncthreads();  // kb reads done -> overwrite with ps

#pragma unroll
  for (int i = 0; i < 4; ++i) {
    const int q = 16 * w + 4 * g + i;
#pragma unroll
    for (int n = 0; n < 8; ++n)
      kbps[q * 136 + 16 * n + r16] = f2b(acc[n][i]);
  }
  if (r16 == 0) {
#pragma unroll
    for (int i = 0; i < 4; ++i) {
      const int q = 16 * w + 4 * g + i;
      slogits[((size_t)b * SS + st[q]) * HH + h] = lse4[i];
    }
  }
  __syncthreads();

  f32x4 o[4];
#pragma unroll
  for (int n = 0; n < 4; ++n) o[n] = (f32x4){0.f, 0.f, 0.f, 0.f};
#pragma unroll
  for (int kk = 0; kk < 4; ++kk) {
    bf16x8 pa = *(const bf16x8*)&kbps[(16 * w + r16) * 136 + kk * 32 + g * 8];
#pragma unroll
    for (int n = 0; n < 4; ++n) {
      bf16x8 vbf = *(const bf16x8*)&vt[16 * n + r16][kk * 32 + g * 8];
      o[n] = __builtin_amdgcn_mfma_f32_16x16x32_bf16(pa, vbf, o[n], 0, 0, 0);
    }
  }

  __syncthreads();  // ps reads done -> overwrite with ob
#pragma unroll
  for (int i = 0; i < 4; ++i) {
    const int q = 16 * w + 4 * g + i;
#pragma unroll
    for (int n = 0; n < 4; ++n)
      kbps[q * 72 + 16 * n + r16] = f2b(o[n][i]);
  }
  __syncthreads();

  {
    const int row = tid >> 2, q4 = tid & 3;
    uint4 x0 = *(const uint4*)&kbps[row * 72 + q4 * 16];
    uint4 x1 = *(const uint4*)&kbps[row * 72 + q4 * 16 + 8];
    unsigned short* dst = so + (((size_t)bl * SS + st[row]) * HH + h) * DD + q4 * 16;
    *(uint4*)&dst[0] = x0;
    *(uint4*)&dst[8] = x1;
  }
}

// ---------------------------------------------------------------------------
// Kernel 4: combine — out[b,t] = sum_h exp(l_h - LSE) * o_h[b,t,h].
// so layout (local b, t, h, d): contiguous per token.
// ---------------------------------------------------------------------------
__global__ __launch_bounds__(256) void gather_out_kernel(const unsigned short* __restrict__ so,
                                                         const float* __restrict__ slogits,
                                                         float* __restrict__ out,
                                                         const int b_base) {
  const int idx = blockIdx.x * 256 + threadIdx.x;  // (local bt, seg)
  const int seg = idx & 7;
  const int btl = idx >> 3;  // local row in [0, 4*SS)

  const float* lrow = slogits + ((size_t)b_base * SS + btl) * HH;
  float4 l0 = ((const float4*)lrow)[0];
  float4 l1 = ((const float4*)lrow)[1];
  float l[8] = {l0.x, l0.y, l0.z, l0.w, l1.x, l1.y, l1.z, l1.w};
  float m = -3.4e38f;
#pragma unroll
  for (int h = 0; h < HH; ++h) m = fmaxf(m, l[h]);
  float sum = 0.f;
#pragma unroll
  for (int h = 0; h < HH; ++h) sum += __expf(l[h] - m);
  const float lse = m + logf(sum);

  float acc[8];
#pragma unroll
  for (int k = 0; k < 8; ++k) acc[k] = 0.f;
#pragma unroll
  for (int h = 0; h < HH; ++h) {
    const float wgt = __expf(l[h] - lse);
    uint4 u = *(const uint4*)(so + ((size_t)btl * HH + h) * DD + seg * 8);
    const unsigned int uu[4] = {u.x, u.y, u.z, u.w};
#pragma unroll
    for (int k = 0; k < 4; ++k) {
      acc[2 * k] += wgt * b2f((unsigned short)(uu[k] & 0xffffu));
      acc[2 * k + 1] += wgt * b2f((unsigned short)(uu[k] >> 16));
    }
  }
  float* dst = out + ((size_t)b_base * SS + btl) * DD + seg * 8;
  float4 o0, o1;
  o0.x = acc[0]; o0.y = acc[1]; o0.z = acc[2]; o0.w = acc[3];
  o1.x = acc[4]; o1.y = acc[5]; o1.z = acc[6]; o1.w = acc[7];
  ((float4*)dst)[0] = o0;
  ((float4*)dst)[1] = o1;
}

// ---------------------------------------------------------------------------
extern "C" void kernel_launch(void* const* d_in, const int* in_sizes, int n_in,
                              void* d_out, int out_size, void* d_ws, size_t ws_size,
                              hipStream_t stream) {
  (void)in_sizes; (void)n_in; (void)out_size; (void)ws_size;
  const float* qk = (const float*)d_in[0];
  const float* v = (const float*)d_in[1];
  const float* rot = (const float*)d_in[2];
  float* out = (float*)d_out;

  char* ws = (char*)d_ws;
  int* sticker = (int*)ws;                                          // @0,   2 MB
  float* slogits = (float*)(ws + ((size_t)2 << 20));                // @2,   2 MB (b,t,h)
  float* snorm = (float*)(ws + ((size_t)4 << 20));                  // @4,   256 KB
  unsigned char* bucket = (unsigned char*)(ws + ((size_t)4 << 20) + ((size_t)256 << 10));  // 512 KB
  unsigned short* qhat = (unsigned short*)(ws + ((size_t)5 << 20)); // @5,   8 MB
  unsigned short* vb = (unsigned short*)(ws + ((size_t)13 << 20));  // @13,  8 MB
  unsigned short* so = (unsigned short*)(ws + ((size_t)21 << 20));  // @21, 32 MB (half-batch)

  prep_kernel<<<(BB * SS * 8) / 256, 256, 0, stream>>>(qk, v, qhat, vb, snorm);
  hash_kernel<<<dim3(NCHUNK, BB), 256, 0, stream>>>(qk, rot, bucket);
  sort_kernel<<<BB * HH, 1024, 0, stream>>>(bucket, sticker);

  for (int half = 0; half < 2; ++half) {
    const int b_base = half * (BB / 2);
    attn_kernel<<<dim3(NB, BB / 2, HH), 256, 0, stream>>>(qhat, vb, snorm, sticker, so, slogits, b_base);
    gather_out_kernel<<<(BB / 2 * SS * 8) / 256, 256, 0, stream>>>(so, slogits, out, b_base);
  }
}